// Round 1
// baseline (431.340 us; speedup 1.0000x reference)
//
#include <hip/hip_runtime.h>
#include <math.h>

// ---------------------------------------------------------------------------
// Deformable-attention decoder layer, fp32 baseline.
// Config (static): N=8, Lq=1024, D=256, NH=8, NL=4, NP=4, DH=32, DFFN=1024
// Levels: (96,96),(48,48),(24,24),(12,12)
// ---------------------------------------------------------------------------

#define NB   8
#define LQ   1024
#define DMODEL 256
#define NHEAD 8
#define NLVL 4
#define NPTS 4
#define DHEAD 32
#define DFFN 1024

// value buffer float offsets (per level, layout (n, y*W+x, d) row-major)
#define VB0 0
#define VB1 18874368   // 8*9216*256
#define VB2 23592960   // +8*2304*256
#define VB3 24772608   // +8*576*256
#define VTOT 25067520  // +8*144*256

// ---------------------------------------------------------------------------
// Generic register-tiled SGEMM: C = A(MxK) @ B(KxN) + bias, optional ReLU.
// BM=BN=64, BK=16, 256 threads, 4x4 per thread. All dims divisible.
// ---------------------------------------------------------------------------
template <int RELU>
__global__ __launch_bounds__(256) void sgemm_bias(
    const float* __restrict__ A, const float* __restrict__ B,
    const float* __restrict__ bias, float* __restrict__ C,
    int M, int N, int K)
{
    const int BM = 64, BN = 64, BK = 16;
    __shared__ float As[BK][BM];
    __shared__ float Bs[BK][BN];

    const int t  = threadIdx.x;
    const int m0 = blockIdx.y * BM;
    const int n0 = blockIdx.x * BN;
    const int tx = t & 15;        // 0..15 -> col group
    const int ty = t >> 4;        // 0..15 -> row group

    const int arow = t >> 2;          // 0..63
    const int akk  = (t & 3) * 4;     // 0,4,8,12
    const int brow = t >> 4;          // 0..15
    const int bcol = (t & 15) * 4;    // 0..60

    float acc[4][4] = {};

    for (int k0 = 0; k0 < K; k0 += BK) {
        const float4 av = *(const float4*)&A[(size_t)(m0 + arow) * K + k0 + akk];
        const float4 bv = *(const float4*)&B[(size_t)(k0 + brow) * N + n0 + bcol];
        __syncthreads();
        As[akk + 0][arow] = av.x;
        As[akk + 1][arow] = av.y;
        As[akk + 2][arow] = av.z;
        As[akk + 3][arow] = av.w;
        *(float4*)&Bs[brow][bcol] = bv;
        __syncthreads();
#pragma unroll
        for (int k = 0; k < BK; ++k) {
            const float4 a4 = *(const float4*)&As[k][ty * 4];
            const float4 b4 = *(const float4*)&Bs[k][tx * 4];
            const float ar[4] = {a4.x, a4.y, a4.z, a4.w};
            const float br[4] = {b4.x, b4.y, b4.z, b4.w};
#pragma unroll
            for (int i = 0; i < 4; ++i)
#pragma unroll
                for (int j = 0; j < 4; ++j)
                    acc[i][j] = fmaf(ar[i], br[j], acc[i][j]);
        }
    }

#pragma unroll
    for (int i = 0; i < 4; ++i) {
        const int row = m0 + ty * 4 + i;
#pragma unroll
        for (int j = 0; j < 4; ++j) {
            const int col = n0 + tx * 4 + j;
            float v = acc[i][j] + bias[col];
            if (RELU) v = fmaxf(v, 0.f);
            C[(size_t)row * N + col] = v;
        }
    }
}

// ---------------------------------------------------------------------------
// loc = reference_points + off / [W_l, H_l]   (in-place on the off buffer)
// off layout col = ((h*4+l)*4+p)*2+xy within each (n,q) row of 256.
// ---------------------------------------------------------------------------
__global__ __launch_bounds__(256) void loc_kernel(
    float* __restrict__ off, const float* __restrict__ ref)
{
    const int i = blockIdx.x * 256 + threadIdx.x;   // 0 .. 2097151
    const int xy = i & 1;
    const int l  = (i >> 3) & 3;
    const int q  = (i >> 8) & 1023;
    const int n  = i >> 18;
    const float norm[4] = {96.f, 48.f, 24.f, 12.f};  // square levels: W==H
    const float r = ref[(((size_t)(n * 1024 + q) * 4) + l) * 2 + xy];
    off[i] = r + off[i] / norm[l];
}

// ---------------------------------------------------------------------------
// Fused softmax + bilinear sampling + head-weighted sum -> ms_out (N,Lq,256)
// One block per (n,q); thread t = h*32 + dh.
// ---------------------------------------------------------------------------
__global__ __launch_bounds__(256) void sampler_kernel(
    const float* __restrict__ vals, const float* __restrict__ loc,
    const float* __restrict__ logits, float* __restrict__ msout)
{
    __shared__ float loc_s[256];
    __shared__ float attn_s[128];

    const int b = blockIdx.x;        // n*1024 + q
    const int n = b >> 10;
    const int t = threadIdx.x;

    loc_s[t] = loc[(size_t)b * 256 + t];
    if (t < 128) attn_s[t] = logits[(size_t)b * 128 + t];
    __syncthreads();

    if (t < 8) {   // per-head softmax over 16 values
        float m = -1e30f;
#pragma unroll
        for (int i = 0; i < 16; ++i) m = fmaxf(m, attn_s[t * 16 + i]);
        float e[16];
        float s = 0.f;
#pragma unroll
        for (int i = 0; i < 16; ++i) { e[i] = expf(attn_s[t * 16 + i] - m); s += e[i]; }
        const float inv = 1.f / s;
#pragma unroll
        for (int i = 0; i < 16; ++i) attn_s[t * 16 + i] = e[i] * inv;
    }
    __syncthreads();

    const int h  = t >> 5;
    const int dh = t & 31;

    const int   HWdim[4] = {96, 48, 24, 12};
    const int   HWsz[4]  = {9216, 2304, 576, 144};
    const size_t vbase[4] = {VB0, VB1, VB2, VB3};

    float acc = 0.f;
#pragma unroll
    for (int l = 0; l < 4; ++l) {
        const int Hl = HWdim[l], Wl = HWdim[l];
        const float* __restrict__ vb =
            vals + vbase[l] + (size_t)n * HWsz[l] * DMODEL + h * DHEAD + dh;
#pragma unroll
        for (int p = 0; p < 4; ++p) {
            const int li = ((h * 4 + l) * 4 + p) * 2;
            const float lx = loc_s[li];
            const float ly = loc_s[li + 1];
            const float a  = attn_s[h * 16 + l * 4 + p];
            const float x = lx * (float)Wl - 0.5f;
            const float y = ly * (float)Hl - 0.5f;
            const float x0f = floorf(x), y0f = floorf(y);
            const float wx = x - x0f, wy = y - y0f;
            const int x0 = (int)x0f, y0 = (int)y0f;
            float s = 0.f;
#pragma unroll
            for (int dy = 0; dy < 2; ++dy) {
                const int yi = y0 + dy;
                if ((unsigned)yi < (unsigned)Hl) {
                    const float wyv = dy ? wy : 1.f - wy;
#pragma unroll
                    for (int dx = 0; dx < 2; ++dx) {
                        const int xi = x0 + dx;
                        if ((unsigned)xi < (unsigned)Wl) {
                            const float w = wyv * (dx ? wx : 1.f - wx);
                            s = fmaf(w, vb[(size_t)(yi * Wl + xi) * DMODEL], s);
                        }
                    }
                }
            }
            acc = fmaf(a, s, acc);
        }
    }
    msout[(size_t)b * 256 + t] = acc;
}

// ---------------------------------------------------------------------------
// out = LayerNorm(a + b) * g + be   (row of 256, one block per row)
// ---------------------------------------------------------------------------
__global__ __launch_bounds__(256) void ln_kernel(
    const float* __restrict__ a, const float* __restrict__ b,
    const float* __restrict__ g, const float* __restrict__ be,
    float* __restrict__ out)
{
    const int row = blockIdx.x;
    const int t   = threadIdx.x;
    const float x = a[(size_t)row * 256 + t] + b[(size_t)row * 256 + t];

    float s = x, s2 = x * x;
#pragma unroll
    for (int off = 32; off; off >>= 1) {
        s  += __shfl_down(s, off);
        s2 += __shfl_down(s2, off);
    }
    __shared__ float ps[4], ps2[4], mv[2];
    const int wid = t >> 6, lane = t & 63;
    if (lane == 0) { ps[wid] = s; ps2[wid] = s2; }
    __syncthreads();
    if (t == 0) {
        float ts = 0.f, ts2 = 0.f;
#pragma unroll
        for (int i = 0; i < 4; ++i) { ts += ps[i]; ts2 += ps2[i]; }
        const float mean = ts * (1.f / 256.f);
        const float var  = ts2 * (1.f / 256.f) - mean * mean;
        mv[0] = mean;
        mv[1] = rsqrtf(var + 1e-5f);
    }
    __syncthreads();
    out[(size_t)row * 256 + t] = (x - mv[0]) * mv[1] * g[t] + be[t];
}

// ---------------------------------------------------------------------------
extern "C" void kernel_launch(void* const* d_in, const int* in_sizes, int n_in,
                              void* d_out, int out_size, void* d_ws, size_t ws_size,
                              hipStream_t stream)
{
    const float* tgt   = (const float*)d_in[0];
    const float* ref   = (const float*)d_in[1];
    const float* src0  = (const float*)d_in[2];
    const float* src1  = (const float*)d_in[3];
    const float* src2  = (const float*)d_in[4];
    const float* src3  = (const float*)d_in[5];
    const float* Wv0   = (const float*)d_in[6];
    const float* bv0   = (const float*)d_in[7];
    const float* Wv1   = (const float*)d_in[8];
    const float* bv1   = (const float*)d_in[9];
    const float* Woff  = (const float*)d_in[10];
    const float* boff  = (const float*)d_in[11];
    const float* Wattn = (const float*)d_in[12];
    const float* battn = (const float*)d_in[13];
    const float* Wout  = (const float*)d_in[14];
    const float* bout  = (const float*)d_in[15];
    const float* g1    = (const float*)d_in[16];
    const float* be1   = (const float*)d_in[17];
    const float* W1    = (const float*)d_in[18];
    const float* b1    = (const float*)d_in[19];
    const float* W2    = (const float*)d_in[20];
    const float* b2    = (const float*)d_in[21];
    const float* g3    = (const float*)d_in[22];
    const float* be3   = (const float*)d_in[23];

    float* ws     = (float*)d_ws;
    float* vals   = ws;                      // 25,067,520
    float* loc    = vals + VTOT;             // 2,097,152  (off -> loc in place)
    float* logits = loc + 2097152;           // 1,048,576
    float* msout  = logits + 1048576;        // 2,097,152
    float* ms2    = msout + 2097152;         // 2,097,152
    float* tbuf   = ms2 + 2097152;           // 2,097,152
    float* ffn1   = tbuf + 2097152;          // 8,388,608
    float* ffn2   = ffn1 + 8388608;          // 2,097,152

    const dim3 blk(256);

    // 1) per-level value projection: values = src @ Wv + bv
    sgemm_bias<0><<<dim3(4, 73728 / 64), blk, 0, stream>>>(src0, Wv0, bv0, vals + VB0, 73728, 256, 16);
    sgemm_bias<0><<<dim3(4, 18432 / 64), blk, 0, stream>>>(src1, Wv1, bv1, vals + VB1, 18432, 256, 32);
    sgemm_bias<0><<<dim3(4, 4608 / 64),  blk, 0, stream>>>(src2, Wv0, bv0, vals + VB2, 4608, 256, 16);
    sgemm_bias<0><<<dim3(4, 1152 / 64),  blk, 0, stream>>>(src3, Wv1, bv1, vals + VB3, 1152, 256, 32);

    // 2) off = tgt @ Woff + boff; logits = tgt @ Wattn + battn
    sgemm_bias<0><<<dim3(4, 128), blk, 0, stream>>>(tgt, Woff, boff, loc, 8192, 256, 256);
    sgemm_bias<0><<<dim3(2, 128), blk, 0, stream>>>(tgt, Wattn, battn, logits, 8192, 128, 256);

    // 3) loc = ref + off/norm (in place)
    loc_kernel<<<8192, blk, 0, stream>>>(loc, ref);

    // 4) softmax + bilinear sample + weighted sum
    sampler_kernel<<<8192, blk, 0, stream>>>(vals, loc, logits, msout);

    // 5) ms2 = msout @ Wout + bout
    sgemm_bias<0><<<dim3(4, 128), blk, 0, stream>>>(msout, Wout, bout, ms2, 8192, 256, 256);

    // 6) t = LN(tgt + ms2)
    ln_kernel<<<8192, blk, 0, stream>>>(tgt, ms2, g1, be1, tbuf);

    // 7) ffn1 = relu(t @ W1 + b1); ffn2 = ffn1 @ W2 + b2
    sgemm_bias<1><<<dim3(16, 128), blk, 0, stream>>>(tbuf, W1, b1, ffn1, 8192, 1024, 256);
    sgemm_bias<0><<<dim3(4, 128),  blk, 0, stream>>>(ffn1, W2, b2, ffn2, 8192, 256, 1024);

    // 8) out = LN(t + ffn2)
    ln_kernel<<<8192, blk, 0, stream>>>(tbuf, ffn2, g3, be3, (float*)d_out);
}

// Round 2
// 260.209 us; speedup vs baseline: 1.6577x; 1.6577x over previous
//
#include <hip/hip_runtime.h>
#include <math.h>

// ---------------------------------------------------------------------------
// Deformable-attention decoder layer, bf16-MFMA version.
// N=8, Lq=1024, D=256, NH=8, NL=4, NP=4, DH=32, DFFN=1024
// ---------------------------------------------------------------------------

typedef __bf16 bf16x8 __attribute__((ext_vector_type(8)));
typedef float  f32x4  __attribute__((ext_vector_type(4)));

// value buffer offsets in elements (bf16), layout (n, pix, h*32+dh) per level
#define VB0 0
#define VB1 18874368   // 8*9216*256
#define VB2 23592960   // +8*2304*256
#define VB3 24772608   // +8*576*256
#define VTOT 25067520

__device__ __forceinline__ unsigned short f2bf(float f) {
    unsigned u = __float_as_uint(f);
    u += 0x7FFF + ((u >> 16) & 1);           // RNE
    return (unsigned short)(u >> 16);
}
__device__ __forceinline__ float bf2f(unsigned short s) {
    return __uint_as_float(((unsigned)s) << 16);
}

__device__ __forceinline__ void gload16(const void* g, void* l) {
    __builtin_amdgcn_global_load_lds(
        (const __attribute__((address_space(1))) unsigned int*)g,
        (__attribute__((address_space(3))) unsigned int*)l, 16, 0, 0);
}

// ---------------------------------------------------------------------------
// prep: tgt->bf16; transpose weights to (N x K) bf16; combined off/attn B + bias
// ---------------------------------------------------------------------------
__global__ __launch_bounds__(256) void prep_kernel(
    const float* __restrict__ tgt, const float* __restrict__ Woff,
    const float* __restrict__ Wattn, const float* __restrict__ Wout,
    const float* __restrict__ W1, const float* __restrict__ W2,
    const float* __restrict__ boff, const float* __restrict__ battn,
    unsigned short* __restrict__ tgt_bf, unsigned short* __restrict__ Btoa,
    unsigned short* __restrict__ WoT, unsigned short* __restrict__ W1T,
    unsigned short* __restrict__ W2T, float* __restrict__ boa)
{
    const int b = blockIdx.x, t = threadIdx.x;
    if (b < 2048) {
        const int i = (b * 256 + t) * 4;
        const float4 v = *(const float4*)&tgt[i];
        ushort4 o;
        o.x = f2bf(v.x); o.y = f2bf(v.y); o.z = f2bf(v.z); o.w = f2bf(v.w);
        *(ushort4*)&tgt_bf[i] = o;
    } else {
        const int idx = (b - 2048) * 256 + t;
        if (idx < 65536) {                       // Woff^T -> Btoa rows 0..255
            const int n = idx >> 8, k = idx & 255;
            Btoa[idx] = f2bf(Woff[k * 256 + n]);
        } else if (idx < 98304) {                // Wattn^T -> Btoa rows 256..383
            const int j = idx - 65536;
            const int n = j >> 8, k = j & 255;
            Btoa[idx] = f2bf(Wattn[k * 128 + n]);
        } else if (idx < 163840) {               // Wout^T
            const int j = idx - 98304;
            const int n = j >> 8, k = j & 255;
            WoT[j] = f2bf(Wout[k * 256 + n]);
        } else if (idx < 425984) {               // W1^T (1024 x 256)
            const int j = idx - 163840;
            const int n = j >> 8, k = j & 255;
            W1T[j] = f2bf(W1[k * 1024 + n]);
        } else if (idx < 688128) {               // W2^T (256 x 1024)
            const int j = idx - 425984;
            const int n = j >> 10, k = j & 1023;
            W2T[j] = f2bf(W2[k * 256 + n]);
        } else if (idx < 688512) {               // combined bias
            const int j = idx - 688128;
            boa[j] = (j < 256) ? boff[j] : battn[j - 256];
        }
    }
}

// ---------------------------------------------------------------------------
// value projection: vals_bf16 = src @ Wv + bv, per level, one dispatch.
// block: 256 thr = 64 pixels x 4 channel-groups of 64. W fp32 in skewed LDS.
// ---------------------------------------------------------------------------
__global__ __launch_bounds__(256) void vproj_kernel(
    const float* __restrict__ src0, const float* __restrict__ src1,
    const float* __restrict__ src2, const float* __restrict__ src3,
    const float* __restrict__ Wv0, const float* __restrict__ bv0,
    const float* __restrict__ Wv1, const float* __restrict__ bv1,
    unsigned short* __restrict__ vals)
{
    __shared__ float sW[32 * 268];   // [k][c + 4*(c>>6)], row stride 268
    __shared__ float sS[64 * 33];    // [p][k], stride K+1

    const int b = blockIdx.x, t = threadIdx.x;
    const float *src, *W, *bias;
    int K, lb; size_t obase;
    if (b < 1152)      { src = src0; W = Wv0; bias = bv0; K = 16; lb = b;        obase = VB0; }
    else if (b < 1440) { src = src1; W = Wv1; bias = bv1; K = 32; lb = b - 1152; obase = VB1; }
    else if (b < 1512) { src = src2; W = Wv0; bias = bv0; K = 16; lb = b - 1440; obase = VB2; }
    else               { src = src3; W = Wv1; bias = bv1; K = 32; lb = b - 1512; obase = VB3; }
    const int pix0 = lb * 64;
    const int SS = K + 1;
    const int kmask = K - 1;
    const int ksh = (K == 16) ? 4 : 5;

    for (int i = t; i < K * 256; i += 256) {
        const int k = i >> 8, c = i & 255;
        sW[k * 268 + c + 4 * (c >> 6)] = W[i];
    }
    for (int i = t; i < 64 * K; i += 256) {
        sS[(i >> ksh) * SS + (i & kmask)] = src[(size_t)pix0 * K + i];
    }
    __syncthreads();

    const int p = t >> 2, cg = t & 3, cb = cg * 64;
    const int wb = cg * 68;      // cb + 4*(cb>>6)

    float acc[64];
    {
        const float4* bp = (const float4*)&bias[cb];
#pragma unroll
        for (int j4 = 0; j4 < 16; ++j4) {
            const float4 bb = bp[j4];
            acc[j4 * 4 + 0] = bb.x; acc[j4 * 4 + 1] = bb.y;
            acc[j4 * 4 + 2] = bb.z; acc[j4 * 4 + 3] = bb.w;
        }
    }
#pragma unroll 4
    for (int k = 0; k < K; ++k) {
        const float ak = sS[p * SS + k];
        const float4* wr = (const float4*)&sW[k * 268 + wb];
#pragma unroll
        for (int j4 = 0; j4 < 16; ++j4) {
            const float4 w = wr[j4];
            acc[j4 * 4 + 0] = fmaf(ak, w.x, acc[j4 * 4 + 0]);
            acc[j4 * 4 + 1] = fmaf(ak, w.y, acc[j4 * 4 + 1]);
            acc[j4 * 4 + 2] = fmaf(ak, w.z, acc[j4 * 4 + 2]);
            acc[j4 * 4 + 3] = fmaf(ak, w.w, acc[j4 * 4 + 3]);
        }
    }
    unsigned short* op = vals + obase + (size_t)(pix0 + p) * 256 + cb;
#pragma unroll
    for (int j4 = 0; j4 < 16; ++j4) {
        ushort4 o;
        o.x = f2bf(acc[j4 * 4 + 0]); o.y = f2bf(acc[j4 * 4 + 1]);
        o.z = f2bf(acc[j4 * 4 + 2]); o.w = f2bf(acc[j4 * 4 + 3]);
        *(ushort4*)&op[j4 * 4] = o;
    }
}

// ---------------------------------------------------------------------------
// bf16 MFMA GEMM: C(MxN) = A(MxK) @ Bt(NxK)^T + bias. Tile 128x64, BK=32,
// 4 waves (2x2), each wave 64x32 = 4x2 fragments of 16x16x32.
// ---------------------------------------------------------------------------
template <int RELU, int OUTBF16>
__global__ __launch_bounds__(256) void gemm_bf16(
    const unsigned short* __restrict__ A, const unsigned short* __restrict__ Bt,
    const float* __restrict__ bias, float* __restrict__ C32,
    unsigned short* __restrict__ C16, int M, int N, int K)
{
    __shared__ unsigned short As[128 * 32];
    __shared__ unsigned short Bs[64 * 32];

    const int t = threadIdx.x, wv = t >> 6, l = t & 63;
    const int m0 = blockIdx.y * 128, n0 = blockIdx.x * 64;
    const int wm = wv >> 1, wn = wv & 1;
    const int lr = l >> 2;                  // row within a 16-row chunk
    const int lc = (l & 3) * 16;            // byte offset within 64B row

    f32x4 zero = {0.f, 0.f, 0.f, 0.f};
    f32x4 acc[4][2];
#pragma unroll
    for (int i = 0; i < 4; ++i) { acc[i][0] = zero; acc[i][1] = zero; }

    const int fr = l & 15, kc = (l >> 4) * 8;

    for (int k0 = 0; k0 < K; k0 += 32) {
        __syncthreads();
        // stage A: 8 chunks of 16 rows x 64B; wave stages chunks 2wv, 2wv+1
#pragma unroll
        for (int cc = 0; cc < 2; ++cc) {
            const int chunk = wv * 2 + cc;
            const int row = chunk * 16 + lr;
            const char* src = (const char*)(A + (size_t)(m0 + row) * K + k0) + lc;
            gload16(src, &As[chunk * 512]);
        }
        // stage B: 4 chunks; wave stages chunk wv
        {
            const int row = wv * 16 + lr;
            const char* src = (const char*)(Bt + (size_t)(n0 + row) * K + k0) + lc;
            gload16(src, &Bs[wv * 512]);
        }
        __syncthreads();

        bf16x8 bfrag[2];
#pragma unroll
        for (int j = 0; j < 2; ++j)
            bfrag[j] = *(const bf16x8*)&Bs[(wn * 32 + j * 16 + fr) * 32 + kc];
#pragma unroll
        for (int i = 0; i < 4; ++i) {
            const bf16x8 af = *(const bf16x8*)&As[(wm * 64 + i * 16 + fr) * 32 + kc];
            acc[i][0] = __builtin_amdgcn_mfma_f32_16x16x32_bf16(af, bfrag[0], acc[i][0], 0, 0, 0);
            acc[i][1] = __builtin_amdgcn_mfma_f32_16x16x32_bf16(af, bfrag[1], acc[i][1], 0, 0, 0);
        }
    }

    const int q4 = (l >> 4) * 4;
#pragma unroll
    for (int j = 0; j < 2; ++j) {
        const int col = n0 + wn * 32 + j * 16 + fr;
        const float bj = bias[col];
#pragma unroll
        for (int i = 0; i < 4; ++i) {
#pragma unroll
            for (int r = 0; r < 4; ++r) {
                const int row = m0 + wm * 64 + i * 16 + q4 + r;
                float v = acc[i][j][r] + bj;
                if (RELU) v = fmaxf(v, 0.f);
                if (OUTBF16) C16[(size_t)row * N + col] = f2bf(v);
                else         C32[(size_t)row * N + col] = v;
            }
        }
    }
}

// ---------------------------------------------------------------------------
// sampler: 1 wave per query. lane = h*8 + lg; each lane owns 4 channels.
// Fuses loc (= ref*W + off - 0.5), per-head softmax, bilinear gather (bf16).
// ---------------------------------------------------------------------------
__global__ __launch_bounds__(256) void sampler_kernel(
    const unsigned short* __restrict__ vals, const float* __restrict__ offlog,
    const float* __restrict__ ref, unsigned short* __restrict__ msout)
{
    __shared__ float sOL[4][384];
    __shared__ float sRef[4][8];

    const int t = threadIdx.x, w = t >> 6, l = t & 63;
    const int b = blockIdx.x * 4 + w;       // query id
    const int n = b >> 10;

#pragma unroll
    for (int j = 0; j < 6; ++j)
        sOL[w][l + 64 * j] = offlog[(size_t)b * 384 + l + 64 * j];
    if (l < 8) sRef[w][l] = ref[b * 8 + l];
    __syncthreads();

    const int h = l >> 3, lg = l & 7;

    // per-head softmax over 16 logits (redundant across 8 lanes; LDS broadcast)
    const float* lgp = &sOL[w][256 + h * 16];
    float mx = -1e30f;
#pragma unroll
    for (int i = 0; i < 16; ++i) mx = fmaxf(mx, lgp[i]);
    float e[16], s = 0.f;
#pragma unroll
    for (int i = 0; i < 16; ++i) { e[i] = __expf(lgp[i] - mx); s += e[i]; }
    const float inv = 1.f / s;

    float acc0 = 0.f, acc1 = 0.f, acc2 = 0.f, acc3 = 0.f;
    const int dims[4] = {96, 48, 24, 12};
    const int hwsz[4] = {9216, 2304, 576, 144};
    const size_t vbase[4] = {VB0, VB1, VB2, VB3};

#pragma unroll
    for (int lv = 0; lv < 4; ++lv) {
        const int W = dims[lv];
        const float fx = sRef[w][lv * 2]     * (float)W - 0.5f;
        const float fy = sRef[w][lv * 2 + 1] * (float)W - 0.5f;
        const unsigned short* vb =
            vals + vbase[lv] + (size_t)n * hwsz[lv] * 256 + h * 32 + lg * 4;
#pragma unroll
        for (int p = 0; p < 4; ++p) {
            const int oi = ((h * 4 + lv) * 4 + p) * 2;
            const float x = fx + sOL[w][oi];
            const float y = fy + sOL[w][oi + 1];
            const float x0f = floorf(x), y0f = floorf(y);
            const float wx = x - x0f, wy = y - y0f;
            const int x0 = (int)x0f, y0 = (int)y0f;
            const float aw = e[lv * 4 + p] * inv;
            float sv0 = 0.f, sv1 = 0.f, sv2 = 0.f, sv3 = 0.f;
#pragma unroll
            for (int dy = 0; dy < 2; ++dy) {
                const int yi = y0 + dy;
                if ((unsigned)yi < (unsigned)W) {
                    const float wyv = dy ? wy : 1.f - wy;
#pragma unroll
                    for (int dx = 0; dx < 2; ++dx) {
                        const int xi = x0 + dx;
                        if ((unsigned)xi < (unsigned)W) {
                            const float ww = wyv * (dx ? wx : 1.f - wx);
                            const ushort4 u = *(const ushort4*)&vb[(size_t)(yi * W + xi) * 256];
                            sv0 = fmaf(ww, bf2f(u.x), sv0);
                            sv1 = fmaf(ww, bf2f(u.y), sv1);
                            sv2 = fmaf(ww, bf2f(u.z), sv2);
                            sv3 = fmaf(ww, bf2f(u.w), sv3);
                        }
                    }
                }
            }
            acc0 = fmaf(aw, sv0, acc0);
            acc1 = fmaf(aw, sv1, acc1);
            acc2 = fmaf(aw, sv2, acc2);
            acc3 = fmaf(aw, sv3, acc3);
        }
    }
    ushort4 o;
    o.x = f2bf(acc0); o.y = f2bf(acc1); o.z = f2bf(acc2); o.w = f2bf(acc3);
    *(ushort4*)&msout[(size_t)b * 256 + h * 32 + lg * 4] = o;
}

// ---------------------------------------------------------------------------
// LN: out = LayerNorm(a+b)*g + be. 1 wave per row of 256, optional bf16 copy.
// ---------------------------------------------------------------------------
__global__ __launch_bounds__(256) void ln_kernel(
    const float* __restrict__ a, const float* __restrict__ b,
    const float* __restrict__ g, const float* __restrict__ be,
    float* __restrict__ out32, unsigned short* __restrict__ out16)
{
    const int t = threadIdx.x, w = t >> 6, l = t & 63;
    const int row = blockIdx.x * 4 + w;
    const size_t base = (size_t)row * 256 + l * 4;
    const float4 av = *(const float4*)&a[base];
    const float4 bv = *(const float4*)&b[base];
    const float x0 = av.x + bv.x, x1 = av.y + bv.y, x2 = av.z + bv.z, x3 = av.w + bv.w;
    float s  = x0 + x1 + x2 + x3;
    float s2 = x0 * x0 + x1 * x1 + x2 * x2 + x3 * x3;
#pragma unroll
    for (int o = 32; o; o >>= 1) { s += __shfl_xor(s, o); s2 += __shfl_xor(s2, o); }
    const float mean = s * (1.f / 256.f);
    const float rstd = rsqrtf(s2 * (1.f / 256.f) - mean * mean + 1e-5f);
    const float4 gv = *(const float4*)&g[l * 4];
    const float4 ev = *(const float4*)&be[l * 4];
    const float y0 = (x0 - mean) * rstd * gv.x + ev.x;
    const float y1 = (x1 - mean) * rstd * gv.y + ev.y;
    const float y2 = (x2 - mean) * rstd * gv.z + ev.z;
    const float y3 = (x3 - mean) * rstd * gv.w + ev.w;
    float4 o4; o4.x = y0; o4.y = y1; o4.z = y2; o4.w = y3;
    *(float4*)&out32[base] = o4;
    if (out16) {
        ushort4 o;
        o.x = f2bf(y0); o.y = f2bf(y1); o.z = f2bf(y2); o.w = f2bf(y3);
        *(ushort4*)&out16[base] = o;
    }
}

// ---------------------------------------------------------------------------
extern "C" void kernel_launch(void* const* d_in, const int* in_sizes, int n_in,
                              void* d_out, int out_size, void* d_ws, size_t ws_size,
                              hipStream_t stream)
{
    const float* tgt   = (const float*)d_in[0];
    const float* ref   = (const float*)d_in[1];
    const float* src0  = (const float*)d_in[2];
    const float* src1  = (const float*)d_in[3];
    const float* src2  = (const float*)d_in[4];
    const float* src3  = (const float*)d_in[5];
    const float* Wv0   = (const float*)d_in[6];
    const float* bv0   = (const float*)d_in[7];
    const float* Wv1   = (const float*)d_in[8];
    const float* bv1   = (const float*)d_in[9];
    const float* Woff  = (const float*)d_in[10];
    const float* boff  = (const float*)d_in[11];
    const float* Wattn = (const float*)d_in[12];
    const float* battn = (const float*)d_in[13];
    const float* Wout  = (const float*)d_in[14];
    const float* bout  = (const float*)d_in[15];
    const float* g1    = (const float*)d_in[16];
    const float* be1   = (const float*)d_in[17];
    const float* W1    = (const float*)d_in[18];
    const float* b1    = (const float*)d_in[19];
    const float* W2    = (const float*)d_in[20];
    const float* b2    = (const float*)d_in[21];
    const float* g3    = (const float*)d_in[22];
    const float* be3   = (const float*)d_in[23];

    char* w8 = (char*)d_ws;
    unsigned short* vals_bf  = (unsigned short*)(w8 + 0);
    unsigned short* tgt_bf   = (unsigned short*)(w8 + 50135040);
    unsigned short* Btoa     = (unsigned short*)(w8 + 54329344);
    unsigned short* WoT      = (unsigned short*)(w8 + 54525952);
    unsigned short* W1T      = (unsigned short*)(w8 + 54657024);
    unsigned short* W2T      = (unsigned short*)(w8 + 55181312);
    unsigned short* ffn1_bf  = (unsigned short*)(w8 + 55705600);
    unsigned short* msout_bf = (unsigned short*)(w8 + 72482816);
    unsigned short* tbuf16   = (unsigned short*)(w8 + 76677120);
    float* boa    = (float*)(w8 + 80871424);
    float* offlog = (float*)(w8 + 80872960);
    float* ms2    = (float*)(w8 + 93455872);
    float* tbuf32 = (float*)(w8 + 101844480);
    float* ffn2   = (float*)(w8 + 110233088);

    const dim3 blk(256);

    prep_kernel<<<4738, blk, 0, stream>>>(tgt, Woff, Wattn, Wout, W1, W2, boff, battn,
                                          tgt_bf, Btoa, WoT, W1T, W2T, boa);
    vproj_kernel<<<1530, blk, 0, stream>>>(src0, src1, src2, src3, Wv0, bv0, Wv1, bv1, vals_bf);

    // offlog = tgt @ [Woff|Wattn] + [boff|battn]   (8192 x 384, K=256)
    gemm_bf16<0, 0><<<dim3(6, 64), blk, 0, stream>>>(tgt_bf, Btoa, boa, offlog,
                                                     (unsigned short*)nullptr, 8192, 384, 256);
    sampler_kernel<<<2048, blk, 0, stream>>>(vals_bf, offlog, ref, msout_bf);

    // ms2 = msout @ Wout + bout
    gemm_bf16<0, 0><<<dim3(4, 64), blk, 0, stream>>>(msout_bf, WoT, bout, ms2,
                                                     (unsigned short*)nullptr, 8192, 256, 256);
    // t = LN(tgt + ms2) -> fp32 + bf16
    ln_kernel<<<2048, blk, 0, stream>>>(tgt, ms2, g1, be1, tbuf32, tbuf16);

    // ffn1 = relu(t @ W1 + b1) -> bf16
    gemm_bf16<1, 1><<<dim3(16, 64), blk, 0, stream>>>(tbuf16, W1T, b1, (float*)nullptr,
                                                      ffn1_bf, 8192, 1024, 256);
    // ffn2 = ffn1 @ W2 + b2 -> fp32
    gemm_bf16<0, 0><<<dim3(4, 64), blk, 0, stream>>>(ffn1_bf, W2T, b2, ffn2,
                                                     (unsigned short*)nullptr, 8192, 256, 1024);
    // out = LN(t + ffn2)
    ln_kernel<<<2048, blk, 0, stream>>>(tbuf32, ffn2, g3, be3, (float*)d_out,
                                        (unsigned short*)nullptr);
}

// Round 4
// 234.726 us; speedup vs baseline: 1.8376x; 1.1086x over previous
//
#include <hip/hip_runtime.h>
#include <math.h>

// ---------------------------------------------------------------------------
// Deformable-attention decoder layer. bf16 MFMA GEMMs (128x128 tile, swizzled
// LDS, 2-phase prefetch) + branchless 2-query/wave sampler.
// N=8, Lq=1024, D=256, NH=8, NL=4, NP=4, DH=32, DFFN=1024
// ---------------------------------------------------------------------------

typedef __bf16 bf16x8 __attribute__((ext_vector_type(8)));
typedef float  f32x4  __attribute__((ext_vector_type(4)));

#define VB0 0
#define VB1 18874368   // 8*9216*256
#define VB2 23592960   // +8*2304*256
#define VB3 24772608   // +8*576*256
#define VTOT 25067520

__device__ __forceinline__ unsigned short f2bf(float f) {
    unsigned u = __float_as_uint(f);
    u += 0x7FFF + ((u >> 16) & 1);           // RNE
    return (unsigned short)(u >> 16);
}

__device__ __forceinline__ void gload16(const void* g, void* l) {
    __builtin_amdgcn_global_load_lds(
        (const __attribute__((address_space(1))) unsigned int*)g,
        (__attribute__((address_space(3))) unsigned int*)l, 16, 0, 0);
}

// ---------------------------------------------------------------------------
// prep: tgt->bf16 (blocks 0..2047); bias concat (2048); coalesced 64x64 tile
// transposes of all weights to (N x K) bf16 (2049..2216).
// ---------------------------------------------------------------------------
__global__ __launch_bounds__(256) void prep_kernel(
    const float* __restrict__ tgt, const float* __restrict__ Woff,
    const float* __restrict__ Wattn, const float* __restrict__ Wout,
    const float* __restrict__ W1, const float* __restrict__ W2,
    const float* __restrict__ boff, const float* __restrict__ battn,
    unsigned short* __restrict__ tgt_bf, unsigned short* __restrict__ Btoa,
    unsigned short* __restrict__ WoT, unsigned short* __restrict__ W1T,
    unsigned short* __restrict__ W2T, float* __restrict__ boa)
{
    __shared__ float sT[64][65];
    const int b = blockIdx.x, t = threadIdx.x;
    if (b < 2048) {
        const int i = (b * 256 + t) * 4;
        const float4 v = *(const float4*)&tgt[i];
        ushort4 o;
        o.x = f2bf(v.x); o.y = f2bf(v.y); o.z = f2bf(v.z); o.w = f2bf(v.w);
        *(ushort4*)&tgt_bf[i] = o;
        return;
    }
    if (b == 2048) {
        if (t < 384) boa[t] = (t < 256) ? boff[t] : battn[t - 256];
        return;
    }
    int tb = b - 2049;
    const float* src; unsigned short* dst; int srcN, dstK, tn, tk;
    if (tb < 16)       { src = Woff;  dst = Btoa;          srcN = 256;  dstK = 256;  tn = tb >> 2; tk = tb & 3; }
    else if (tb < 24)  { tb -= 16; src = Wattn; dst = Btoa + 65536; srcN = 128; dstK = 256; tn = tb >> 2; tk = tb & 3; }
    else if (tb < 40)  { tb -= 24; src = Wout;  dst = WoT; srcN = 256;  dstK = 256;  tn = tb >> 2; tk = tb & 3; }
    else if (tb < 104) { tb -= 40; src = W1;    dst = W1T; srcN = 1024; dstK = 256;  tn = tb >> 2; tk = tb & 3; }
    else               { tb -= 104; src = W2;   dst = W2T; srcN = 256;  dstK = 1024; tn = tb >> 4; tk = tb & 15; }
    const int n0 = tn * 64, k0 = tk * 64;
    const int j = t & 63, i0 = t >> 6;
#pragma unroll
    for (int s = 0; s < 16; ++s) {
        const int i = i0 + s * 4;
        sT[i][j] = src[(size_t)(k0 + i) * srcN + n0 + j];
    }
    __syncthreads();
#pragma unroll
    for (int s = 0; s < 16; ++s) {
        const int nr = i0 + s * 4;
        dst[(size_t)(n0 + nr) * dstK + k0 + j] = f2bf(sT[j][nr]);
    }
}

// ---------------------------------------------------------------------------
// value projection (unchanged)
// ---------------------------------------------------------------------------
__global__ __launch_bounds__(256) void vproj_kernel(
    const float* __restrict__ src0, const float* __restrict__ src1,
    const float* __restrict__ src2, const float* __restrict__ src3,
    const float* __restrict__ Wv0, const float* __restrict__ bv0,
    const float* __restrict__ Wv1, const float* __restrict__ bv1,
    unsigned short* __restrict__ vals)
{
    __shared__ float sW[32 * 268];
    __shared__ float sS[64 * 33];

    const int b = blockIdx.x, t = threadIdx.x;
    const float *src, *W, *bias;
    int K, lb; size_t obase;
    if (b < 1152)      { src = src0; W = Wv0; bias = bv0; K = 16; lb = b;        obase = VB0; }
    else if (b < 1440) { src = src1; W = Wv1; bias = bv1; K = 32; lb = b - 1152; obase = VB1; }
    else if (b < 1512) { src = src2; W = Wv0; bias = bv0; K = 16; lb = b - 1440; obase = VB2; }
    else               { src = src3; W = Wv1; bias = bv1; K = 32; lb = b - 1512; obase = VB3; }
    const int pix0 = lb * 64;
    const int SS = K + 1;
    const int kmask = K - 1;
    const int ksh = (K == 16) ? 4 : 5;

    for (int i = t; i < K * 256; i += 256) {
        const int k = i >> 8, c = i & 255;
        sW[k * 268 + c + 4 * (c >> 6)] = W[i];
    }
    for (int i = t; i < 64 * K; i += 256) {
        sS[(i >> ksh) * SS + (i & kmask)] = src[(size_t)pix0 * K + i];
    }
    __syncthreads();

    const int p = t >> 2, cg = t & 3, cb = cg * 64;
    const int wb = cg * 68;

    float acc[64];
    {
        const float4* bp = (const float4*)&bias[cb];
#pragma unroll
        for (int j4 = 0; j4 < 16; ++j4) {
            const float4 bb = bp[j4];
            acc[j4 * 4 + 0] = bb.x; acc[j4 * 4 + 1] = bb.y;
            acc[j4 * 4 + 2] = bb.z; acc[j4 * 4 + 3] = bb.w;
        }
    }
#pragma unroll 4
    for (int k = 0; k < K; ++k) {
        const float ak = sS[p * SS + k];
        const float4* wr = (const float4*)&sW[k * 268 + wb];
#pragma unroll
        for (int j4 = 0; j4 < 16; ++j4) {
            const float4 w = wr[j4];
            acc[j4 * 4 + 0] = fmaf(ak, w.x, acc[j4 * 4 + 0]);
            acc[j4 * 4 + 1] = fmaf(ak, w.y, acc[j4 * 4 + 1]);
            acc[j4 * 4 + 2] = fmaf(ak, w.z, acc[j4 * 4 + 2]);
            acc[j4 * 4 + 3] = fmaf(ak, w.w, acc[j4 * 4 + 3]);
        }
    }
    unsigned short* op = vals + obase + (size_t)(pix0 + p) * 256 + cb;
#pragma unroll
    for (int j4 = 0; j4 < 16; ++j4) {
        ushort4 o;
        o.x = f2bf(acc[j4 * 4 + 0]); o.y = f2bf(acc[j4 * 4 + 1]);
        o.z = f2bf(acc[j4 * 4 + 2]); o.w = f2bf(acc[j4 * 4 + 3]);
        *(ushort4*)&op[j4 * 4] = o;
    }
}

// ---------------------------------------------------------------------------
// bf16 MFMA GEMM: C(MxN) = A(MxK) @ Bt(NxK)^T + bias.
// Tile 128x128, BK=32, 4 waves (2x2), 4x4 16x16x32 frags/wave.
// XOR-swizzled LDS (slot ^= (row>>1)&3), double-buffered, 2-phase prefetch.
// ---------------------------------------------------------------------------
template <int RELU, int OUTBF16>
__global__ __launch_bounds__(256) void gemm_bf16(
    const unsigned short* __restrict__ A, const unsigned short* __restrict__ Bt,
    const float* __restrict__ bias, float* __restrict__ C32,
    unsigned short* __restrict__ C16, int M, int N, int K)
{
    __shared__ unsigned short As[2][128 * 32];
    __shared__ unsigned short Bs[2][128 * 32];

    const int t = threadIdx.x, wv = t >> 6, l = t & 63;
    const int m0 = blockIdx.y * 128, n0 = blockIdx.x * 128;
    const int wm = wv >> 1, wn = wv & 1;
    const int lr = l >> 2, sl = l & 3;
    const int swsl = sl ^ ((lr >> 1) & 3);     // pre-swizzled source slot
    const int fr = l & 15, kg = l >> 4;
    const int rsw = (fr >> 1) & 3;             // read-side swizzle

    f32x4 acc[4][4];
#pragma unroll
    for (int i = 0; i < 4; ++i)
#pragma unroll
        for (int j = 0; j < 4; ++j) acc[i][j] = (f32x4){0.f, 0.f, 0.f, 0.f};

#define STAGE(bufi, k0)                                                        \
    do {                                                                       \
        _Pragma("unroll")                                                      \
        for (int cc = 0; cc < 2; ++cc) {                                       \
            const int rb = wv * 32 + cc * 16;                                  \
            gload16(A + (size_t)(m0 + rb + lr) * K + (k0) + swsl * 8,          \
                    &As[bufi][rb * 32]);                                       \
            gload16(Bt + (size_t)(n0 + rb + lr) * K + (k0) + swsl * 8,         \
                    &Bs[bufi][rb * 32]);                                       \
        }                                                                      \
    } while (0)

    const int NT = K >> 5;
    STAGE(0, 0);
    asm volatile("s_waitcnt vmcnt(0)" ::: "memory");
    __syncthreads();

    for (int tt = 0; tt < NT; ++tt) {
        const int cur = tt & 1;
        if (tt + 1 < NT) STAGE(cur ^ 1, (tt + 1) * 32);

        bf16x8 af[4], bfr[4];
#pragma unroll
        for (int i = 0; i < 4; ++i)
            af[i] = *(const bf16x8*)&As[cur][(wm * 64 + i * 16 + fr) * 32 + (kg ^ rsw) * 8];
#pragma unroll
        for (int j = 0; j < 4; ++j)
            bfr[j] = *(const bf16x8*)&Bs[cur][(wn * 64 + j * 16 + fr) * 32 + (kg ^ rsw) * 8];
#pragma unroll
        for (int i = 0; i < 4; ++i)
#pragma unroll
            for (int j = 0; j < 4; ++j)
                acc[i][j] = __builtin_amdgcn_mfma_f32_16x16x32_bf16(af[i], bfr[j], acc[i][j], 0, 0, 0);

        asm volatile("s_waitcnt vmcnt(0)" ::: "memory");
        __syncthreads();
    }
#undef STAGE

    const int q4 = (l >> 4) * 4;
#pragma unroll
    for (int j = 0; j < 4; ++j) {
        const int col = n0 + wn * 64 + j * 16 + fr;
        const float bj = bias[col];
#pragma unroll
        for (int i = 0; i < 4; ++i) {
#pragma unroll
            for (int r = 0; r < 4; ++r) {
                const int row = m0 + wm * 64 + i * 16 + q4 + r;
                float v = acc[i][j][r] + bj;
                if (RELU) v = fmaxf(v, 0.f);
                if (OUTBF16) C16[(size_t)row * N + col] = f2bf(v);
                else         C32[(size_t)row * N + col] = v;
            }
        }
    }
}

// ---------------------------------------------------------------------------
// sampler: 2 queries per wave, 4 lanes per head, 8 channels (16B) per lane.
// Branchless corners (clamped address x zeroed weight). Conflict-free LDS.
// ---------------------------------------------------------------------------
__device__ __forceinline__ void acc8(const unsigned short* p, float w, float* a)
{
    const uint4 u = *(const uint4*)p;
    a[0] = fmaf(w, __uint_as_float(u.x << 16), a[0]);
    a[1] = fmaf(w, __uint_as_float(u.x & 0xffff0000u), a[1]);
    a[2] = fmaf(w, __uint_as_float(u.y << 16), a[2]);
    a[3] = fmaf(w, __uint_as_float(u.y & 0xffff0000u), a[3]);
    a[4] = fmaf(w, __uint_as_float(u.z << 16), a[4]);
    a[5] = fmaf(w, __uint_as_float(u.z & 0xffff0000u), a[5]);
    a[6] = fmaf(w, __uint_as_float(u.w << 16), a[6]);
    a[7] = fmaf(w, __uint_as_float(u.w & 0xffff0000u), a[7]);
}

__global__ __launch_bounds__(256) void sampler_kernel(
    const unsigned short* __restrict__ vals, const float* __restrict__ offlog,
    const float* __restrict__ ref, unsigned short* __restrict__ msout)
{
    __shared__ float sOff[8][256];   // [(lv*4+p)*16 + h*2 + xy]
    __shared__ float sLog[8][128];   // [i*8+h]
    __shared__ float sRef[8][8];

    const int t = threadIdx.x, w = t >> 6, l = t & 63;
    const int qbase = blockIdx.x * 8;

    for (int j = l; j < 768; j += 64) {
        const int second = (j >= 384);
        const int lq = w * 2 + second;
        const int jj = second ? j - 384 : j;      // FIX: 384 is not pow2; & 383 was wrong
        const float v = offlog[(size_t)(qbase + lq) * 384 + jj];
        if (jj < 256) {
            const int h = jj >> 5, r = jj & 31;
            sOff[lq][(r >> 1) * 16 + h * 2 + (r & 1)] = v;
        } else {
            const int j2 = jj - 256;
            sLog[lq][(j2 & 15) * 8 + (j2 >> 4)] = v;
        }
    }
    if (l < 16)
        sRef[w * 2 + (l >> 3)][l & 7] = ref[(size_t)(qbase + w * 2 + (l >> 3)) * 8 + (l & 7)];
    __syncthreads();

    const int lq = w * 2 + (l >> 5);
    const int b  = qbase + lq;
    const int n  = b >> 10;
    const int h  = (l >> 2) & 7;
    const int lg = l & 3;

    float mx = -1e30f;
#pragma unroll
    for (int i = 0; i < 16; ++i) mx = fmaxf(mx, sLog[lq][i * 8 + h]);
    float e[16], s = 0.f;
#pragma unroll
    for (int i = 0; i < 16; ++i) { e[i] = __expf(sLog[lq][i * 8 + h] - mx); s += e[i]; }
    const float inv = 1.f / s;

    float acc[8] = {0.f, 0.f, 0.f, 0.f, 0.f, 0.f, 0.f, 0.f};
    const int dims[4] = {96, 48, 24, 12};
    const int hwsz[4] = {9216, 2304, 576, 144};
    const size_t vbase[4] = {VB0, VB1, VB2, VB3};

#pragma unroll
    for (int lv = 0; lv < 4; ++lv) {
        const int W = dims[lv];
        const float fx = sRef[lq][lv * 2]     * (float)W - 0.5f;
        const float fy = sRef[lq][lv * 2 + 1] * (float)W - 0.5f;
        const unsigned short* vb =
            vals + vbase[lv] + (size_t)n * hwsz[lv] * 256 + h * 32 + lg * 8;
#pragma unroll
        for (int p = 0; p < 4; ++p) {
            const float2 xy = *(const float2*)&sOff[lq][((lv * 4 + p) * 8 + h) * 2];
            const float x = fx + xy.x;
            const float y = fy + xy.y;
            const float x0f = floorf(x), y0f = floorf(y);
            const float wx = x - x0f, wy = y - y0f;
            const int x0 = (int)x0f, y0 = (int)y0f;
            const float aw = e[lv * 4 + p] * inv;
            const float vx0 = ((unsigned)x0       < (unsigned)W) ? 1.f - wx : 0.f;
            const float vx1 = ((unsigned)(x0 + 1) < (unsigned)W) ? wx       : 0.f;
            const float vy0 = ((unsigned)y0       < (unsigned)W) ? 1.f - wy : 0.f;
            const float vy1 = ((unsigned)(y0 + 1) < (unsigned)W) ? wy       : 0.f;
            const int cx0 = min(max(x0, 0), W - 1);
            const int cx1 = min(max(x0 + 1, 0), W - 1);
            const int cy0 = min(max(y0, 0), W - 1) * W;
            const int cy1 = min(max(y0 + 1, 0), W - 1) * W;
            acc8(vb + (size_t)(cy0 + cx0) * 256, aw * vy0 * vx0, acc);
            acc8(vb + (size_t)(cy0 + cx1) * 256, aw * vy0 * vx1, acc);
            acc8(vb + (size_t)(cy1 + cx0) * 256, aw * vy1 * vx0, acc);
            acc8(vb + (size_t)(cy1 + cx1) * 256, aw * vy1 * vx1, acc);
        }
    }
    uint4 o;
    o.x = (unsigned)f2bf(acc[0]) | ((unsigned)f2bf(acc[1]) << 16);
    o.y = (unsigned)f2bf(acc[2]) | ((unsigned)f2bf(acc[3]) << 16);
    o.z = (unsigned)f2bf(acc[4]) | ((unsigned)f2bf(acc[5]) << 16);
    o.w = (unsigned)f2bf(acc[6]) | ((unsigned)f2bf(acc[7]) << 16);
    *(uint4*)&msout[(size_t)b * 256 + h * 32 + lg * 8] = o;
}

// ---------------------------------------------------------------------------
// LN: out = LayerNorm(a+b)*g + be. 1 wave per row of 256, optional bf16 copy.
// ---------------------------------------------------------------------------
__global__ __launch_bounds__(256) void ln_kernel(
    const float* __restrict__ a, const float* __restrict__ b,
    const float* __restrict__ g, const float* __restrict__ be,
    float* __restrict__ out32, unsigned short* __restrict__ out16)
{
    const int t = threadIdx.x, w = t >> 6, l = t & 63;
    const int row = blockIdx.x * 4 + w;
    const size_t base = (size_t)row * 256 + l * 4;
    const float4 av = *(const float4*)&a[base];
    const float4 bv = *(const float4*)&b[base];
    const float x0 = av.x + bv.x, x1 = av.y + bv.y, x2 = av.z + bv.z, x3 = av.w + bv.w;
    float s  = x0 + x1 + x2 + x3;
    float s2 = x0 * x0 + x1 * x1 + x2 * x2 + x3 * x3;
#pragma unroll
    for (int o = 32; o; o >>= 1) { s += __shfl_xor(s, o); s2 += __shfl_xor(s2, o); }
    const float mean = s * (1.f / 256.f);
    const float rstd = rsqrtf(s2 * (1.f / 256.f) - mean * mean + 1e-5f);
    const float4 gv = *(const float4*)&g[l * 4];
    const float4 ev = *(const float4*)&be[l * 4];
    const float y0 = (x0 - mean) * rstd * gv.x + ev.x;
    const float y1 = (x1 - mean) * rstd * gv.y + ev.y;
    const float y2 = (x2 - mean) * rstd * gv.z + ev.z;
    const float y3 = (x3 - mean) * rstd * gv.w + ev.w;
    float4 o4; o4.x = y0; o4.y = y1; o4.z = y2; o4.w = y3;
    *(float4*)&out32[base] = o4;
    if (out16) {
        ushort4 o;
        o.x = f2bf(y0); o.y = f2bf(y1); o.z = f2bf(y2); o.w = f2bf(y3);
        *(ushort4*)&out16[base] = o;
    }
}

// ---------------------------------------------------------------------------
extern "C" void kernel_launch(void* const* d_in, const int* in_sizes, int n_in,
                              void* d_out, int out_size, void* d_ws, size_t ws_size,
                              hipStream_t stream)
{
    const float* tgt   = (const float*)d_in[0];
    const float* ref   = (const float*)d_in[1];
    const float* src0  = (const float*)d_in[2];
    const float* src1  = (const float*)d_in[3];
    const float* src2  = (const float*)d_in[4];
    const float* src3  = (const float*)d_in[5];
    const float* Wv0   = (const float*)d_in[6];
    const float* bv0   = (const float*)d_in[7];
    const float* Wv1   = (const float*)d_in[8];
    const float* bv1   = (const float*)d_in[9];
    const float* Woff  = (const float*)d_in[10];
    const float* boff  = (const float*)d_in[11];
    const float* Wattn = (const float*)d_in[12];
    const float* battn = (const float*)d_in[13];
    const float* Wout  = (const float*)d_in[14];
    const float* bout  = (const float*)d_in[15];
    const float* g1    = (const float*)d_in[16];
    const float* be1   = (const float*)d_in[17];
    const float* W1    = (const float*)d_in[18];
    const float* b1    = (const float*)d_in[19];
    const float* W2    = (const float*)d_in[20];
    const float* b2    = (const float*)d_in[21];
    const float* g3    = (const float*)d_in[22];
    const float* be3   = (const float*)d_in[23];

    char* w8 = (char*)d_ws;
    unsigned short* vals_bf  = (unsigned short*)(w8 + 0);
    unsigned short* tgt_bf   = (unsigned short*)(w8 + 50135040);
    unsigned short* Btoa     = (unsigned short*)(w8 + 54329344);
    unsigned short* WoT      = (unsigned short*)(w8 + 54525952);
    unsigned short* W1T      = (unsigned short*)(w8 + 54657024);
    unsigned short* W2T      = (unsigned short*)(w8 + 55181312);
    unsigned short* ffn1_bf  = (unsigned short*)(w8 + 55705600);
    unsigned short* msout_bf = (unsigned short*)(w8 + 72482816);
    unsigned short* tbuf16   = (unsigned short*)(w8 + 76677120);
    float* boa    = (float*)(w8 + 80871424);
    float* offlog = (float*)(w8 + 80872960);
    float* ms2    = (float*)(w8 + 93455872);
    float* tbuf32 = (float*)(w8 + 101844480);
    float* ffn2   = (float*)(w8 + 110233088);

    const dim3 blk(256);

    prep_kernel<<<2217, blk, 0, stream>>>(tgt, Woff, Wattn, Wout, W1, W2, boff, battn,
                                          tgt_bf, Btoa, WoT, W1T, W2T, boa);
    vproj_kernel<<<1530, blk, 0, stream>>>(src0, src1, src2, src3, Wv0, bv0, Wv1, bv1, vals_bf);

    // offlog = tgt @ [Woff|Wattn] + [boff|battn]   (8192 x 384, K=256)
    gemm_bf16<0, 0><<<dim3(3, 64), blk, 0, stream>>>(tgt_bf, Btoa, boa, offlog,
                                                     (unsigned short*)nullptr, 8192, 384, 256);
    sampler_kernel<<<1024, blk, 0, stream>>>(vals_bf, offlog, ref, msout_bf);

    // ms2 = msout @ Wout + bout
    gemm_bf16<0, 0><<<dim3(2, 64), blk, 0, stream>>>(msout_bf, WoT, bout, ms2,
                                                     (unsigned short*)nullptr, 8192, 256, 256);
    // t = LN(tgt + ms2) -> fp32 + bf16
    ln_kernel<<<2048, blk, 0, stream>>>(tgt, ms2, g1, be1, tbuf32, tbuf16);

    // ffn1 = relu(t @ W1 + b1) -> bf16
    gemm_bf16<1, 1><<<dim3(8, 64), blk, 0, stream>>>(tbuf16, W1T, b1, (float*)nullptr,
                                                     ffn1_bf, 8192, 1024, 256);
    // ffn2 = ffn1 @ W2 + b2 -> fp32
    gemm_bf16<0, 0><<<dim3(2, 64), blk, 0, stream>>>(ffn1_bf, W2T, b2, ffn2,
                                                     (unsigned short*)nullptr, 8192, 256, 1024);
    // out = LN(t + ffn2)
    ln_kernel<<<2048, blk, 0, stream>>>(tbuf32, ffn2, g3, be3, (float*)d_out,
                                        (unsigned short*)nullptr);
}

// Round 8
// 222.946 us; speedup vs baseline: 1.9347x; 1.0528x over previous
//
#include <hip/hip_runtime.h>
#include <math.h>

// ---------------------------------------------------------------------------
// Deformable-attention decoder layer. bf16 MFMA GEMMs (128x128 tile, swizzled
// LDS, 2-phase prefetch) for ALL matmuls incl. value projection (K padded to
// 32), + branchless 2-query/wave sampler.
// N=8, Lq=1024, D=256, NH=8, NL=4, NP=4, DH=32, DFFN=1024
// ---------------------------------------------------------------------------

typedef __bf16 bf16x8 __attribute__((ext_vector_type(8)));
typedef float  f32x4  __attribute__((ext_vector_type(4)));

#define VB0 0
#define VB1 18874368   // 8*9216*256
#define VB2 23592960   // +8*2304*256
#define VB3 24772608   // +8*576*256
#define VTOT 25067520

__device__ __forceinline__ unsigned short f2bf(float f) {
    unsigned u = __float_as_uint(f);
    u += 0x7FFF + ((u >> 16) & 1);           // RNE
    return (unsigned short)(u >> 16);
}

__device__ __forceinline__ void gload16(const void* g, void* l) {
    __builtin_amdgcn_global_load_lds(
        (const __attribute__((address_space(1))) unsigned int*)g,
        (__attribute__((address_space(3))) unsigned int*)l, 16, 0, 0);
}

// ---------------------------------------------------------------------------
// prep:
//   blocks 0..2047    : tgt -> bf16
//   block  2048       : bias concat + WvT0/WvT1 (256x32 bf16, K-padded)
//   blocks 2049..2216 : coalesced 64x64 tile transposes of Woff/Wattn/Wout/W1/W2
//   blocks 2217..4052 : src0..3 -> bf16 (K=16 levels zero-padded to 32)
// ---------------------------------------------------------------------------
__global__ __launch_bounds__(256) void prep_kernel(
    const float* __restrict__ tgt, const float* __restrict__ Woff,
    const float* __restrict__ Wattn, const float* __restrict__ Wout,
    const float* __restrict__ W1, const float* __restrict__ W2,
    const float* __restrict__ boff, const float* __restrict__ battn,
    const float* __restrict__ src0, const float* __restrict__ src1,
    const float* __restrict__ src2, const float* __restrict__ src3,
    const float* __restrict__ Wv0, const float* __restrict__ Wv1,
    unsigned short* __restrict__ tgt_bf, unsigned short* __restrict__ Btoa,
    unsigned short* __restrict__ WoT, unsigned short* __restrict__ W1T,
    unsigned short* __restrict__ W2T, float* __restrict__ boa,
    unsigned short* __restrict__ src0p, unsigned short* __restrict__ src1b,
    unsigned short* __restrict__ src2p, unsigned short* __restrict__ src3b,
    unsigned short* __restrict__ WvT0, unsigned short* __restrict__ WvT1)
{
    __shared__ float sT[64][65];
    const int b = blockIdx.x, t = threadIdx.x;
    if (b < 2048) {
        const int i = (b * 256 + t) * 4;
        const float4 v = *(const float4*)&tgt[i];
        ushort4 o;
        o.x = f2bf(v.x); o.y = f2bf(v.y); o.z = f2bf(v.z); o.w = f2bf(v.w);
        *(ushort4*)&tgt_bf[i] = o;
        return;
    }
    if (b == 2048) {
        if (t < 384) boa[t] = (t < 256) ? boff[t] : battn[t - 256];
#pragma unroll
        for (int k = 0; k < 16; ++k) {
            WvT0[t * 32 + k]      = f2bf(Wv0[k * 256 + t]);
            WvT0[t * 32 + 16 + k] = 0;
        }
#pragma unroll
        for (int k = 0; k < 32; ++k)
            WvT1[t * 32 + k] = f2bf(Wv1[k * 256 + t]);
        return;
    }
    if (b >= 2217) {
        const int q = (b - 2217) * 256 + t;        // float4 index
        if (q < 294912) {                          // src0 (K=16 -> 32)
            const float4 v = *(const float4*)&src0[(size_t)q * 4];
            ushort4 o;
            o.x = f2bf(v.x); o.y = f2bf(v.y); o.z = f2bf(v.z); o.w = f2bf(v.w);
            const int px = q >> 2, qt = q & 3;
            *(ushort4*)&src0p[(size_t)px * 32 + qt * 4] = o;
            *(ushort4*)&src0p[(size_t)px * 32 + 16 + qt * 4] = (ushort4){0, 0, 0, 0};
        } else if (q < 442368) {                   // src1 (K=32)
            const int q2 = q - 294912;
            const float4 v = *(const float4*)&src1[(size_t)q2 * 4];
            ushort4 o;
            o.x = f2bf(v.x); o.y = f2bf(v.y); o.z = f2bf(v.z); o.w = f2bf(v.w);
            *(ushort4*)&src1b[(size_t)q2 * 4] = o;
        } else if (q < 460800) {                   // src2 (K=16 -> 32)
            const int q3 = q - 442368;
            const float4 v = *(const float4*)&src2[(size_t)q3 * 4];
            ushort4 o;
            o.x = f2bf(v.x); o.y = f2bf(v.y); o.z = f2bf(v.z); o.w = f2bf(v.w);
            const int px = q3 >> 2, qt = q3 & 3;
            *(ushort4*)&src2p[(size_t)px * 32 + qt * 4] = o;
            *(ushort4*)&src2p[(size_t)px * 32 + 16 + qt * 4] = (ushort4){0, 0, 0, 0};
        } else if (q < 470016) {                   // src3 (K=32)
            const int q4 = q - 460800;
            const float4 v = *(const float4*)&src3[(size_t)q4 * 4];
            ushort4 o;
            o.x = f2bf(v.x); o.y = f2bf(v.y); o.z = f2bf(v.z); o.w = f2bf(v.w);
            *(ushort4*)&src3b[(size_t)q4 * 4] = o;
        }
        return;
    }
    int tb = b - 2049;
    const float* src; unsigned short* dst; int srcN, dstK, tn, tk;
    if (tb < 16)       { src = Woff;  dst = Btoa;          srcN = 256;  dstK = 256;  tn = tb >> 2; tk = tb & 3; }
    else if (tb < 24)  { tb -= 16; src = Wattn; dst = Btoa + 65536; srcN = 128; dstK = 256; tn = tb >> 2; tk = tb & 3; }
    else if (tb < 40)  { tb -= 24; src = Wout;  dst = WoT; srcN = 256;  dstK = 256;  tn = tb >> 2; tk = tb & 3; }
    else if (tb < 104) { tb -= 40; src = W1;    dst = W1T; srcN = 1024; dstK = 256;  tn = tb >> 2; tk = tb & 3; }
    else               { tb -= 104; src = W2;   dst = W2T; srcN = 256;  dstK = 1024; tn = tb >> 4; tk = tb & 15; }
    const int n0 = tn * 64, k0 = tk * 64;
    const int j = t & 63, i0 = t >> 6;
#pragma unroll
    for (int s = 0; s < 16; ++s) {
        const int i = i0 + s * 4;
        sT[i][j] = src[(size_t)(k0 + i) * srcN + n0 + j];
    }
    __syncthreads();
#pragma unroll
    for (int s = 0; s < 16; ++s) {
        const int nr = i0 + s * 4;
        dst[(size_t)(n0 + nr) * dstK + k0 + j] = f2bf(sT[j][nr]);
    }
}

// ---------------------------------------------------------------------------
// bf16 MFMA GEMM: C(MxN) = A(MxK) @ Bt(NxK)^T + bias.
// Tile 128x128, BK=32, 4 waves (2x2), 4x4 16x16x32 frags/wave.
// XOR-swizzled LDS (slot ^= (row>>1)&3), double-buffered, 2-phase prefetch.
// ---------------------------------------------------------------------------
template <int RELU, int OUTBF16>
__global__ __launch_bounds__(256) void gemm_bf16(
    const unsigned short* __restrict__ A, const unsigned short* __restrict__ Bt,
    const float* __restrict__ bias, float* __restrict__ C32,
    unsigned short* __restrict__ C16, int M, int N, int K)
{
    __shared__ unsigned short As[2][128 * 32];
    __shared__ unsigned short Bs[2][128 * 32];

    const int t = threadIdx.x, wv = t >> 6, l = t & 63;
    const int m0 = blockIdx.y * 128, n0 = blockIdx.x * 128;
    const int wm = wv >> 1, wn = wv & 1;
    const int lr = l >> 2, sl = l & 3;
    const int swsl = sl ^ ((lr >> 1) & 3);     // pre-swizzled source slot
    const int fr = l & 15, kg = l >> 4;
    const int rsw = (fr >> 1) & 3;             // read-side swizzle

    f32x4 acc[4][4];
#pragma unroll
    for (int i = 0; i < 4; ++i)
#pragma unroll
        for (int j = 0; j < 4; ++j) acc[i][j] = (f32x4){0.f, 0.f, 0.f, 0.f};

#define STAGE(bufi, k0)                                                        \
    do {                                                                       \
        _Pragma("unroll")                                                      \
        for (int cc = 0; cc < 2; ++cc) {                                       \
            const int rb = wv * 32 + cc * 16;                                  \
            gload16(A + (size_t)(m0 + rb + lr) * K + (k0) + swsl * 8,          \
                    &As[bufi][rb * 32]);                                       \
            gload16(Bt + (size_t)(n0 + rb + lr) * K + (k0) + swsl * 8,         \
                    &Bs[bufi][rb * 32]);                                       \
        }                                                                      \
    } while (0)

    const int NT = K >> 5;
    STAGE(0, 0);
    asm volatile("s_waitcnt vmcnt(0)" ::: "memory");
    __syncthreads();

    for (int tt = 0; tt < NT; ++tt) {
        const int cur = tt & 1;
        if (tt + 1 < NT) STAGE(cur ^ 1, (tt + 1) * 32);

        bf16x8 af[4], bfr[4];
#pragma unroll
        for (int i = 0; i < 4; ++i)
            af[i] = *(const bf16x8*)&As[cur][(wm * 64 + i * 16 + fr) * 32 + (kg ^ rsw) * 8];
#pragma unroll
        for (int j = 0; j < 4; ++j)
            bfr[j] = *(const bf16x8*)&Bs[cur][(wn * 64 + j * 16 + fr) * 32 + (kg ^ rsw) * 8];
#pragma unroll
        for (int i = 0; i < 4; ++i)
#pragma unroll
            for (int j = 0; j < 4; ++j)
                acc[i][j] = __builtin_amdgcn_mfma_f32_16x16x32_bf16(af[i], bfr[j], acc[i][j], 0, 0, 0);

        asm volatile("s_waitcnt vmcnt(0)" ::: "memory");
        __syncthreads();
    }
#undef STAGE

    const int q4 = (l >> 4) * 4;
#pragma unroll
    for (int j = 0; j < 4; ++j) {
        const int col = n0 + wn * 64 + j * 16 + fr;
        const float bj = bias[col];
#pragma unroll
        for (int i = 0; i < 4; ++i) {
#pragma unroll
            for (int r = 0; r < 4; ++r) {
                const int row = m0 + wm * 64 + i * 16 + q4 + r;
                float v = acc[i][j][r] + bj;
                if (RELU) v = fmaxf(v, 0.f);
                if (OUTBF16) C16[(size_t)row * N + col] = f2bf(v);
                else         C32[(size_t)row * N + col] = v;
            }
        }
    }
}

// ---------------------------------------------------------------------------
// sampler: 2 queries per wave, 4 lanes per head, 8 channels (16B) per lane.
// Branchless corners (clamped address x zeroed weight). Conflict-free LDS.
// ---------------------------------------------------------------------------
__device__ __forceinline__ void acc8(const unsigned short* p, float w, float* a)
{
    const uint4 u = *(const uint4*)p;
    a[0] = fmaf(w, __uint_as_float(u.x << 16), a[0]);
    a[1] = fmaf(w, __uint_as_float(u.x & 0xffff0000u), a[1]);
    a[2] = fmaf(w, __uint_as_float(u.y << 16), a[2]);
    a[3] = fmaf(w, __uint_as_float(u.y & 0xffff0000u), a[3]);
    a[4] = fmaf(w, __uint_as_float(u.z << 16), a[4]);
    a[5] = fmaf(w, __uint_as_float(u.z & 0xffff0000u), a[5]);
    a[6] = fmaf(w, __uint_as_float(u.w << 16), a[6]);
    a[7] = fmaf(w, __uint_as_float(u.w & 0xffff0000u), a[7]);
}

__global__ __launch_bounds__(256) void sampler_kernel(
    const unsigned short* __restrict__ vals, const float* __restrict__ offlog,
    const float* __restrict__ ref, unsigned short* __restrict__ msout)
{
    __shared__ float sOff[8][256];   // [(lv*4+p)*16 + h*2 + xy]
    __shared__ float sLog[8][128];   // [i*8+h]
    __shared__ float sRef[8][8];

    const int t = threadIdx.x, w = t >> 6, l = t & 63;
    const int qbase = blockIdx.x * 8;

    for (int j = l; j < 768; j += 64) {
        const int second = (j >= 384);
        const int lq = w * 2 + second;
        const int jj = second ? j - 384 : j;      // 384 is not pow2: no masking
        const float v = offlog[(size_t)(qbase + lq) * 384 + jj];
        if (jj < 256) {
            const int h = jj >> 5, r = jj & 31;
            sOff[lq][(r >> 1) * 16 + h * 2 + (r & 1)] = v;
        } else {
            const int j2 = jj - 256;
            sLog[lq][(j2 & 15) * 8 + (j2 >> 4)] = v;
        }
    }
    if (l < 16)
        sRef[w * 2 + (l >> 3)][l & 7] = ref[(size_t)(qbase + w * 2 + (l >> 3)) * 8 + (l & 7)];
    __syncthreads();

    const int lq = w * 2 + (l >> 5);
    const int b  = qbase + lq;
    const int n  = b >> 10;
    const int h  = (l >> 2) & 7;
    const int lg = l & 3;

    float mx = -1e30f;
#pragma unroll
    for (int i = 0; i < 16; ++i) mx = fmaxf(mx, sLog[lq][i * 8 + h]);
    float e[16], s = 0.f;
#pragma unroll
    for (int i = 0; i < 16; ++i) { e[i] = __expf(sLog[lq][i * 8 + h] - mx); s += e[i]; }
    const float inv = 1.f / s;

    float acc[8] = {0.f, 0.f, 0.f, 0.f, 0.f, 0.f, 0.f, 0.f};
    const int dims[4] = {96, 48, 24, 12};
    const int hwsz[4] = {9216, 2304, 576, 144};
    const size_t vbase[4] = {VB0, VB1, VB2, VB3};

#pragma unroll
    for (int lv = 0; lv < 4; ++lv) {
        const int W = dims[lv];
        const float fx = sRef[lq][lv * 2]     * (float)W - 0.5f;
        const float fy = sRef[lq][lv * 2 + 1] * (float)W - 0.5f;
        const unsigned short* vb =
            vals + vbase[lv] + (size_t)n * hwsz[lv] * 256 + h * 32 + lg * 8;
#pragma unroll
        for (int p = 0; p < 4; ++p) {
            const float2 xy = *(const float2*)&sOff[lq][((lv * 4 + p) * 8 + h) * 2];
            const float x = fx + xy.x;
            const float y = fy + xy.y;
            const float x0f = floorf(x), y0f = floorf(y);
            const float wx = x - x0f, wy = y - y0f;
            const int x0 = (int)x0f, y0 = (int)y0f;
            const float aw = e[lv * 4 + p] * inv;
            const float vx0 = ((unsigned)x0       < (unsigned)W) ? 1.f - wx : 0.f;
            const float vx1 = ((unsigned)(x0 + 1) < (unsigned)W) ? wx       : 0.f;
            const float vy0 = ((unsigned)y0       < (unsigned)W) ? 1.f - wy : 0.f;
            const float vy1 = ((unsigned)(y0 + 1) < (unsigned)W) ? wy       : 0.f;
            const int cx0 = min(max(x0, 0), W - 1);
            const int cx1 = min(max(x0 + 1, 0), W - 1);
            const int cy0 = min(max(y0, 0), W - 1) * W;
            const int cy1 = min(max(y0 + 1, 0), W - 1) * W;
            acc8(vb + (size_t)(cy0 + cx0) * 256, aw * vy0 * vx0, acc);
            acc8(vb + (size_t)(cy0 + cx1) * 256, aw * vy0 * vx1, acc);
            acc8(vb + (size_t)(cy1 + cx0) * 256, aw * vy1 * vx0, acc);
            acc8(vb + (size_t)(cy1 + cx1) * 256, aw * vy1 * vx1, acc);
        }
    }
    uint4 o;
    o.x = (unsigned)f2bf(acc[0]) | ((unsigned)f2bf(acc[1]) << 16);
    o.y = (unsigned)f2bf(acc[2]) | ((unsigned)f2bf(acc[3]) << 16);
    o.z = (unsigned)f2bf(acc[4]) | ((unsigned)f2bf(acc[5]) << 16);
    o.w = (unsigned)f2bf(acc[6]) | ((unsigned)f2bf(acc[7]) << 16);
    *(uint4*)&msout[(size_t)b * 256 + h * 32 + lg * 8] = o;
}

// ---------------------------------------------------------------------------
// LN: out = LayerNorm(a+b)*g + be. 1 wave per row of 256, optional bf16 copy.
// ---------------------------------------------------------------------------
__global__ __launch_bounds__(256) void ln_kernel(
    const float* __restrict__ a, const float* __restrict__ b,
    const float* __restrict__ g, const float* __restrict__ be,
    float* __restrict__ out32, unsigned short* __restrict__ out16)
{
    const int t = threadIdx.x, w = t >> 6, l = t & 63;
    const int row = blockIdx.x * 4 + w;
    const size_t base = (size_t)row * 256 + l * 4;
    const float4 av = *(const float4*)&a[base];
    const float4 bv = *(const float4*)&b[base];
    const float x0 = av.x + bv.x, x1 = av.y + bv.y, x2 = av.z + bv.z, x3 = av.w + bv.w;
    float s  = x0 + x1 + x2 + x3;
    float s2 = x0 * x0 + x1 * x1 + x2 * x2 + x3 * x3;
#pragma unroll
    for (int o = 32; o; o >>= 1) { s += __shfl_xor(s, o); s2 += __shfl_xor(s2, o); }
    const float mean = s * (1.f / 256.f);
    const float rstd = rsqrtf(s2 * (1.f / 256.f) - mean * mean + 1e-5f);
    const float4 gv = *(const float4*)&g[l * 4];
    const float4 ev = *(const float4*)&be[l * 4];
    const float y0 = (x0 - mean) * rstd * gv.x + ev.x;
    const float y1 = (x1 - mean) * rstd * gv.y + ev.y;
    const float y2 = (x2 - mean) * rstd * gv.z + ev.z;
    const float y3 = (x3 - mean) * rstd * gv.w + ev.w;
    float4 o4; o4.x = y0; o4.y = y1; o4.z = y2; o4.w = y3;
    *(float4*)&out32[base] = o4;
    if (out16) {
        ushort4 o;
        o.x = f2bf(y0); o.y = f2bf(y1); o.z = f2bf(y2); o.w = f2bf(y3);
        *(ushort4*)&out16[base] = o;
    }
}

// ---------------------------------------------------------------------------
extern "C" void kernel_launch(void* const* d_in, const int* in_sizes, int n_in,
                              void* d_out, int out_size, void* d_ws, size_t ws_size,
                              hipStream_t stream)
{
    const float* tgt   = (const float*)d_in[0];
    const float* ref   = (const float*)d_in[1];
    const float* src0  = (const float*)d_in[2];
    const float* src1  = (const float*)d_in[3];
    const float* src2  = (const float*)d_in[4];
    const float* src3  = (const float*)d_in[5];
    const float* Wv0   = (const float*)d_in[6];
    const float* bv0   = (const float*)d_in[7];
    const float* Wv1   = (const float*)d_in[8];
    const float* bv1   = (const float*)d_in[9];
    const float* Woff  = (const float*)d_in[10];
    const float* boff  = (const float*)d_in[11];
    const float* Wattn = (const float*)d_in[12];
    const float* battn = (const float*)d_in[13];
    const float* Wout  = (const float*)d_in[14];
    const float* bout  = (const float*)d_in[15];
    const float* g1    = (const float*)d_in[16];
    const float* be1   = (const float*)d_in[17];
    const float* W1    = (const float*)d_in[18];
    const float* b1    = (const float*)d_in[19];
    const float* W2    = (const float*)d_in[20];
    const float* b2    = (const float*)d_in[21];
    const float* g3    = (const float*)d_in[22];
    const float* be3   = (const float*)d_in[23];

    char* w8 = (char*)d_ws;
    unsigned short* vals_bf  = (unsigned short*)(w8 + 0);
    unsigned short* tgt_bf   = (unsigned short*)(w8 + 50135040);
    unsigned short* Btoa     = (unsigned short*)(w8 + 54329344);
    unsigned short* WoT      = (unsigned short*)(w8 + 54525952);
    unsigned short* W1T      = (unsigned short*)(w8 + 54657024);
    unsigned short* W2T      = (unsigned short*)(w8 + 55181312);
    unsigned short* ffn1_bf  = (unsigned short*)(w8 + 55705600);
    unsigned short* msout_bf = (unsigned short*)(w8 + 72482816);
    unsigned short* tbuf16   = (unsigned short*)(w8 + 76677120);
    float* boa    = (float*)(w8 + 80871424);
    float* offlog = (float*)(w8 + 80872960);
    float* ms2    = (float*)(w8 + 93455872);
    float* tbuf32 = (float*)(w8 + 101844480);
    float* ffn2   = (float*)(w8 + 110233088);
    // src staging lives inside the ms2 region (written only later by Wout-GEMM)
    unsigned short* src0p = (unsigned short*)(w8 + 93455872);            // 4,718,592 B
    unsigned short* src1b = (unsigned short*)(w8 + 93455872 + 4718592);  // 1,179,648 B
    unsigned short* src2p = (unsigned short*)(w8 + 93455872 + 5898240);  //   294,912 B
    unsigned short* src3b = (unsigned short*)(w8 + 93455872 + 6193152);  //    73,728 B
    unsigned short* WvT0  = (unsigned short*)(w8 + 93455872 + 6266880);  //    16,384 B
    unsigned short* WvT1  = (unsigned short*)(w8 + 93455872 + 6283264);  //    16,384 B

    const dim3 blk(256);

    prep_kernel<<<4053, blk, 0, stream>>>(tgt, Woff, Wattn, Wout, W1, W2, boff, battn,
                                          src0, src1, src2, src3, Wv0, Wv1,
                                          tgt_bf, Btoa, WoT, W1T, W2T, boa,
                                          src0p, src1b, src2p, src3b, WvT0, WvT1);

    // value projection = MFMA GEMMs, K=32 (zero-padded for 16-ch levels)
    gemm_bf16<0, 1><<<dim3(2, 576), blk, 0, stream>>>(src0p, WvT0, bv0, (float*)nullptr,
                                                      vals_bf + VB0, 73728, 256, 32);
    gemm_bf16<0, 1><<<dim3(2, 144), blk, 0, stream>>>(src1b, WvT1, bv1, (float*)nullptr,
                                                      vals_bf + VB1, 18432, 256, 32);
    gemm_bf16<0, 1><<<dim3(2, 36),  blk, 0, stream>>>(src2p, WvT0, bv0, (float*)nullptr,
                                                      vals_bf + VB2, 4608, 256, 32);
    gemm_bf16<0, 1><<<dim3(2, 9),   blk, 0, stream>>>(src3b, WvT1, bv1, (float*)nullptr,
                                                      vals_bf + VB3, 1152, 256, 32);

    // offlog = tgt @ [Woff|Wattn] + [boff|battn]   (8192 x 384, K=256)
    gemm_bf16<0, 0><<<dim3(3, 64), blk, 0, stream>>>(tgt_bf, Btoa, boa, offlog,
                                                     (unsigned short*)nullptr, 8192, 384, 256);
    sampler_kernel<<<1024, blk, 0, stream>>>(vals_bf, offlog, ref, msout_bf);

    // ms2 = msout @ Wout + bout
    gemm_bf16<0, 0><<<dim3(2, 64), blk, 0, stream>>>(msout_bf, WoT, bout, ms2,
                                                     (unsigned short*)nullptr, 8192, 256, 256);
    // t = LN(tgt + ms2) -> fp32 + bf16
    ln_kernel<<<2048, blk, 0, stream>>>(tgt, ms2, g1, be1, tbuf32, tbuf16);

    // ffn1 = relu(t @ W1 + b1) -> bf16
    gemm_bf16<1, 1><<<dim3(8, 64), blk, 0, stream>>>(tbuf16, W1T, b1, (float*)nullptr,
                                                     ffn1_bf, 8192, 1024, 256);
    // ffn2 = ffn1 @ W2 + b2 -> fp32
    gemm_bf16<0, 0><<<dim3(2, 64), blk, 0, stream>>>(ffn1_bf, W2T, b2, ffn2,
                                                     (unsigned short*)nullptr, 8192, 256, 1024);
    // out = LN(t + ffn2)
    ln_kernel<<<2048, blk, 0, stream>>>(tbuf32, ffn2, g3, be3, (float*)d_out,
                                        (unsigned short*)nullptr);
}

// Round 9
// 208.351 us; speedup vs baseline: 2.0703x; 1.0700x over previous
//
#include <hip/hip_runtime.h>
#include <math.h>

// ---------------------------------------------------------------------------
// Deformable-attention decoder layer. bf16 MFMA GEMMs (templated tiles,
// swizzled LDS, 2-phase prefetch); single-dispatch value projection;
// branchless 2-query/wave sampler.
// N=8, Lq=1024, D=256, NH=8, NL=4, NP=4, DH=32, DFFN=1024
// ---------------------------------------------------------------------------

typedef __bf16 bf16x8 __attribute__((ext_vector_type(8)));
typedef float  f32x4  __attribute__((ext_vector_type(4)));

#define VB0 0
#define VB1 18874368   // 8*9216*256
#define VB2 23592960   // +8*2304*256
#define VB3 24772608   // +8*576*256
#define VTOT 25067520

__device__ __forceinline__ unsigned short f2bf(float f) {
    unsigned u = __float_as_uint(f);
    u += 0x7FFF + ((u >> 16) & 1);           // RNE
    return (unsigned short)(u >> 16);
}

__device__ __forceinline__ void gload16(const void* g, void* l) {
    __builtin_amdgcn_global_load_lds(
        (const __attribute__((address_space(1))) unsigned int*)g,
        (__attribute__((address_space(3))) unsigned int*)l, 16, 0, 0);
}

// ---------------------------------------------------------------------------
// prep (unchanged from round 8)
// ---------------------------------------------------------------------------
__global__ __launch_bounds__(256) void prep_kernel(
    const float* __restrict__ tgt, const float* __restrict__ Woff,
    const float* __restrict__ Wattn, const float* __restrict__ Wout,
    const float* __restrict__ W1, const float* __restrict__ W2,
    const float* __restrict__ boff, const float* __restrict__ battn,
    const float* __restrict__ src0, const float* __restrict__ src1,
    const float* __restrict__ src2, const float* __restrict__ src3,
    const float* __restrict__ Wv0, const float* __restrict__ Wv1,
    unsigned short* __restrict__ tgt_bf, unsigned short* __restrict__ Btoa,
    unsigned short* __restrict__ WoT, unsigned short* __restrict__ W1T,
    unsigned short* __restrict__ W2T, float* __restrict__ boa,
    unsigned short* __restrict__ src0p, unsigned short* __restrict__ src1b,
    unsigned short* __restrict__ src2p, unsigned short* __restrict__ src3b,
    unsigned short* __restrict__ WvT0, unsigned short* __restrict__ WvT1)
{
    __shared__ float sT[64][65];
    const int b = blockIdx.x, t = threadIdx.x;
    if (b < 2048) {
        const int i = (b * 256 + t) * 4;
        const float4 v = *(const float4*)&tgt[i];
        ushort4 o;
        o.x = f2bf(v.x); o.y = f2bf(v.y); o.z = f2bf(v.z); o.w = f2bf(v.w);
        *(ushort4*)&tgt_bf[i] = o;
        return;
    }
    if (b == 2048) {
        if (t < 384) boa[t] = (t < 256) ? boff[t] : battn[t - 256];
#pragma unroll
        for (int k = 0; k < 16; ++k) {
            WvT0[t * 32 + k]      = f2bf(Wv0[k * 256 + t]);
            WvT0[t * 32 + 16 + k] = 0;
        }
#pragma unroll
        for (int k = 0; k < 32; ++k)
            WvT1[t * 32 + k] = f2bf(Wv1[k * 256 + t]);
        return;
    }
    if (b >= 2217) {
        const int q = (b - 2217) * 256 + t;        // float4 index
        if (q < 294912) {                          // src0 (K=16 -> 32)
            const float4 v = *(const float4*)&src0[(size_t)q * 4];
            ushort4 o;
            o.x = f2bf(v.x); o.y = f2bf(v.y); o.z = f2bf(v.z); o.w = f2bf(v.w);
            const int px = q >> 2, qt = q & 3;
            *(ushort4*)&src0p[(size_t)px * 32 + qt * 4] = o;
            *(ushort4*)&src0p[(size_t)px * 32 + 16 + qt * 4] = (ushort4){0, 0, 0, 0};
        } else if (q < 442368) {                   // src1 (K=32)
            const int q2 = q - 294912;
            const float4 v = *(const float4*)&src1[(size_t)q2 * 4];
            ushort4 o;
            o.x = f2bf(v.x); o.y = f2bf(v.y); o.z = f2bf(v.z); o.w = f2bf(v.w);
            *(ushort4*)&src1b[(size_t)q2 * 4] = o;
        } else if (q < 460800) {                   // src2 (K=16 -> 32)
            const int q3 = q - 442368;
            const float4 v = *(const float4*)&src2[(size_t)q3 * 4];
            ushort4 o;
            o.x = f2bf(v.x); o.y = f2bf(v.y); o.z = f2bf(v.z); o.w = f2bf(v.w);
            const int px = q3 >> 2, qt = q3 & 3;
            *(ushort4*)&src2p[(size_t)px * 32 + qt * 4] = o;
            *(ushort4*)&src2p[(size_t)px * 32 + 16 + qt * 4] = (ushort4){0, 0, 0, 0};
        } else if (q < 470016) {                   // src3 (K=32)
            const int q4 = q - 460800;
            const float4 v = *(const float4*)&src3[(size_t)q4 * 4];
            ushort4 o;
            o.x = f2bf(v.x); o.y = f2bf(v.y); o.z = f2bf(v.z); o.w = f2bf(v.w);
            *(ushort4*)&src3b[(size_t)q4 * 4] = o;
        }
        return;
    }
    int tb = b - 2049;
    const float* src; unsigned short* dst; int srcN, dstK, tn, tk;
    if (tb < 16)       { src = Woff;  dst = Btoa;          srcN = 256;  dstK = 256;  tn = tb >> 2; tk = tb & 3; }
    else if (tb < 24)  { tb -= 16; src = Wattn; dst = Btoa + 65536; srcN = 128; dstK = 256; tn = tb >> 2; tk = tb & 3; }
    else if (tb < 40)  { tb -= 24; src = Wout;  dst = WoT; srcN = 256;  dstK = 256;  tn = tb >> 2; tk = tb & 3; }
    else if (tb < 104) { tb -= 40; src = W1;    dst = W1T; srcN = 1024; dstK = 256;  tn = tb >> 2; tk = tb & 3; }
    else               { tb -= 104; src = W2;   dst = W2T; srcN = 256;  dstK = 1024; tn = tb >> 4; tk = tb & 15; }
    const int n0 = tn * 64, k0 = tk * 64;
    const int j = t & 63, i0 = t >> 6;
#pragma unroll
    for (int s = 0; s < 16; ++s) {
        const int i = i0 + s * 4;
        sT[i][j] = src[(size_t)(k0 + i) * srcN + n0 + j];
    }
    __syncthreads();
#pragma unroll
    for (int s = 0; s < 16; ++s) {
        const int nr = i0 + s * 4;
        dst[(size_t)(n0 + nr) * dstK + k0 + j] = f2bf(sT[j][nr]);
    }
}

// ---------------------------------------------------------------------------
// bf16 MFMA GEMM, templated tile: C(MxN) = A(MxK) @ Bt(NxK)^T + bias.
// BK=32, 4 waves (2x2); wave covers (BM/2)x(BN/2); frags (BM/32)x(BN/32).
// XOR-swizzled LDS, double-buffered, 2-phase prefetch.
// ---------------------------------------------------------------------------
template <int BM, int BN, int RELU, int OUTBF16>
__global__ __launch_bounds__(256) void gemm_bf16(
    const unsigned short* __restrict__ A, const unsigned short* __restrict__ Bt,
    const float* __restrict__ bias, float* __restrict__ C32,
    unsigned short* __restrict__ C16, int M, int N, int K)
{
    constexpr int MF = BM / 32, NF = BN / 32;      // frags per wave
    constexpr int CA = BM / 16, CB = BN / 16;      // 16-row staging chunks
    constexpr int CPW = (CA + CB) / 4;             // chunks per wave

    __shared__ unsigned short As[2][BM * 32];
    __shared__ unsigned short Bs[2][BN * 32];

    const int t = threadIdx.x, wv = t >> 6, l = t & 63;
    const int m0 = blockIdx.y * BM, n0 = blockIdx.x * BN;
    const int wm = wv >> 1, wn = wv & 1;
    const int lr = l >> 2, sl = l & 3;
    const int swsl = sl ^ ((lr >> 1) & 3);     // pre-swizzled source slot
    const int fr = l & 15, kg = l >> 4;
    const int rsw = (fr >> 1) & 3;             // read-side swizzle

    f32x4 acc[MF][NF];
#pragma unroll
    for (int i = 0; i < MF; ++i)
#pragma unroll
        for (int j = 0; j < NF; ++j) acc[i][j] = (f32x4){0.f, 0.f, 0.f, 0.f};

#define STAGE(bufi, k0)                                                        \
    do {                                                                       \
        _Pragma("unroll")                                                      \
        for (int cc = 0; cc < CPW; ++cc) {                                     \
            const int ch = wv * CPW + cc;                                      \
            if (ch < CA) {                                                     \
                gload16(A + (size_t)(m0 + ch * 16 + lr) * K + (k0) + swsl * 8, \
                        &As[bufi][ch * 512]);                                  \
            } else {                                                           \
                const int cb2 = ch - CA;                                       \
                gload16(Bt + (size_t)(n0 + cb2 * 16 + lr) * K + (k0) + swsl * 8,\
                        &Bs[bufi][cb2 * 512]);                                 \
            }                                                                  \
        }                                                                      \
    } while (0)

    const int NT = K >> 5;
    STAGE(0, 0);
    asm volatile("s_waitcnt vmcnt(0)" ::: "memory");
    __syncthreads();

    for (int tt = 0; tt < NT; ++tt) {
        const int cur = tt & 1;
        if (tt + 1 < NT) STAGE(cur ^ 1, (tt + 1) * 32);

        bf16x8 af[MF], bfr[NF];
#pragma unroll
        for (int i = 0; i < MF; ++i)
            af[i] = *(const bf16x8*)&As[cur][(wm * (MF * 16) + i * 16 + fr) * 32 + (kg ^ rsw) * 8];
#pragma unroll
        for (int j = 0; j < NF; ++j)
            bfr[j] = *(const bf16x8*)&Bs[cur][(wn * (NF * 16) + j * 16 + fr) * 32 + (kg ^ rsw) * 8];
#pragma unroll
        for (int i = 0; i < MF; ++i)
#pragma unroll
            for (int j = 0; j < NF; ++j)
                acc[i][j] = __builtin_amdgcn_mfma_f32_16x16x32_bf16(af[i], bfr[j], acc[i][j], 0, 0, 0);

        asm volatile("s_waitcnt vmcnt(0)" ::: "memory");
        __syncthreads();
    }
#undef STAGE

    const int q4 = (l >> 4) * 4;
#pragma unroll
    for (int j = 0; j < NF; ++j) {
        const int col = n0 + wn * (NF * 16) + j * 16 + fr;
        const float bj = bias[col];
#pragma unroll
        for (int i = 0; i < MF; ++i) {
#pragma unroll
            for (int r = 0; r < 4; ++r) {
                const int row = m0 + wm * (MF * 16) + i * 16 + q4 + r;
                float v = acc[i][j][r] + bj;
                if (RELU) v = fmaxf(v, 0.f);
                if (OUTBF16) C16[(size_t)row * N + col] = f2bf(v);
                else         C32[(size_t)row * N + col] = v;
            }
        }
    }
}

// ---------------------------------------------------------------------------
// value projection: single dispatch, all 4 levels. 128x128 tile, K=32.
// blockIdx.y: [0,576) L0 | [576,720) L1 | [720,756) L2 | [756,765) L3.
// ---------------------------------------------------------------------------
__global__ __launch_bounds__(256) void vproj_gemm(
    const unsigned short* __restrict__ src0p, const unsigned short* __restrict__ src1b,
    const unsigned short* __restrict__ src2p, const unsigned short* __restrict__ src3b,
    const unsigned short* __restrict__ WvT0, const unsigned short* __restrict__ WvT1,
    const float* __restrict__ bv0, const float* __restrict__ bv1,
    unsigned short* __restrict__ vals)
{
    __shared__ unsigned short As[128 * 32];
    __shared__ unsigned short Bs[128 * 32];

    const int ly = blockIdx.y;
    const unsigned short *A, *Bt; const float* bias; size_t ob; int lm;
    if (ly < 576)      { A = src0p; Bt = WvT0; bias = bv0; ob = VB0; lm = ly; }
    else if (ly < 720) { A = src1b; Bt = WvT1; bias = bv1; ob = VB1; lm = ly - 576; }
    else if (ly < 756) { A = src2p; Bt = WvT0; bias = bv0; ob = VB2; lm = ly - 720; }
    else               { A = src3b; Bt = WvT1; bias = bv1; ob = VB3; lm = ly - 756; }

    const int t = threadIdx.x, wv = t >> 6, l = t & 63;
    const int m0 = lm * 128, n0 = blockIdx.x * 128;
    const int wm = wv >> 1, wn = wv & 1;
    const int lr = l >> 2, sl = l & 3;
    const int swsl = sl ^ ((lr >> 1) & 3);
    const int fr = l & 15, kg = l >> 4;
    const int rsw = (fr >> 1) & 3;

    // stage: A 8 chunks + B 8 chunks; wave stages 4 (2A + 2B)
#pragma unroll
    for (int cc = 0; cc < 2; ++cc) {
        const int ch = wv * 2 + cc;
        gload16(A + (size_t)(m0 + ch * 16 + lr) * 32 + swsl * 8, &As[ch * 512]);
        gload16(Bt + (size_t)(n0 + ch * 16 + lr) * 32 + swsl * 8, &Bs[ch * 512]);
    }
    asm volatile("s_waitcnt vmcnt(0)" ::: "memory");
    __syncthreads();

    f32x4 acc[4][4];
#pragma unroll
    for (int i = 0; i < 4; ++i)
#pragma unroll
        for (int j = 0; j < 4; ++j) acc[i][j] = (f32x4){0.f, 0.f, 0.f, 0.f};

    bf16x8 af[4], bfr[4];
#pragma unroll
    for (int i = 0; i < 4; ++i)
        af[i] = *(const bf16x8*)&As[(wm * 64 + i * 16 + fr) * 32 + (kg ^ rsw) * 8];
#pragma unroll
    for (int j = 0; j < 4; ++j)
        bfr[j] = *(const bf16x8*)&Bs[(wn * 64 + j * 16 + fr) * 32 + (kg ^ rsw) * 8];
#pragma unroll
    for (int i = 0; i < 4; ++i)
#pragma unroll
        for (int j = 0; j < 4; ++j)
            acc[i][j] = __builtin_amdgcn_mfma_f32_16x16x32_bf16(af[i], bfr[j], acc[i][j], 0, 0, 0);

    const int q4 = (l >> 4) * 4;
#pragma unroll
    for (int j = 0; j < 4; ++j) {
        const int col = n0 + wn * 64 + j * 16 + fr;
        const float bj = bias[col];
#pragma unroll
        for (int i = 0; i < 4; ++i) {
#pragma unroll
            for (int r = 0; r < 4; ++r) {
                const int row = m0 + wm * 64 + i * 16 + q4 + r;
                vals[ob + (size_t)row * 256 + col] = f2bf(acc[i][j][r] + bj);
            }
        }
    }
}

// ---------------------------------------------------------------------------
// sampler (unchanged from round 8)
// ---------------------------------------------------------------------------
__device__ __forceinline__ void acc8(const unsigned short* p, float w, float* a)
{
    const uint4 u = *(const uint4*)p;
    a[0] = fmaf(w, __uint_as_float(u.x << 16), a[0]);
    a[1] = fmaf(w, __uint_as_float(u.x & 0xffff0000u), a[1]);
    a[2] = fmaf(w, __uint_as_float(u.y << 16), a[2]);
    a[3] = fmaf(w, __uint_as_float(u.y & 0xffff0000u), a[3]);
    a[4] = fmaf(w, __uint_as_float(u.z << 16), a[4]);
    a[5] = fmaf(w, __uint_as_float(u.z & 0xffff0000u), a[5]);
    a[6] = fmaf(w, __uint_as_float(u.w << 16), a[6]);
    a[7] = fmaf(w, __uint_as_float(u.w & 0xffff0000u), a[7]);
}

__global__ __launch_bounds__(256) void sampler_kernel(
    const unsigned short* __restrict__ vals, const float* __restrict__ offlog,
    const float* __restrict__ ref, unsigned short* __restrict__ msout)
{
    __shared__ float sOff[8][256];
    __shared__ float sLog[8][128];
    __shared__ float sRef[8][8];

    const int t = threadIdx.x, w = t >> 6, l = t & 63;
    const int qbase = blockIdx.x * 8;

    for (int j = l; j < 768; j += 64) {
        const int second = (j >= 384);
        const int lq = w * 2 + second;
        const int jj = second ? j - 384 : j;      // 384 is not pow2: no masking
        const float v = offlog[(size_t)(qbase + lq) * 384 + jj];
        if (jj < 256) {
            const int h = jj >> 5, r = jj & 31;
            sOff[lq][(r >> 1) * 16 + h * 2 + (r & 1)] = v;
        } else {
            const int j2 = jj - 256;
            sLog[lq][(j2 & 15) * 8 + (j2 >> 4)] = v;
        }
    }
    if (l < 16)
        sRef[w * 2 + (l >> 3)][l & 7] = ref[(size_t)(qbase + w * 2 + (l >> 3)) * 8 + (l & 7)];
    __syncthreads();

    const int lq = w * 2 + (l >> 5);
    const int b  = qbase + lq;
    const int n  = b >> 10;
    const int h  = (l >> 2) & 7;
    const int lg = l & 3;

    float mx = -1e30f;
#pragma unroll
    for (int i = 0; i < 16; ++i) mx = fmaxf(mx, sLog[lq][i * 8 + h]);
    float e[16], s = 0.f;
#pragma unroll
    for (int i = 0; i < 16; ++i) { e[i] = __expf(sLog[lq][i * 8 + h] - mx); s += e[i]; }
    const float inv = 1.f / s;

    float acc[8] = {0.f, 0.f, 0.f, 0.f, 0.f, 0.f, 0.f, 0.f};
    const int dims[4] = {96, 48, 24, 12};
    const int hwsz[4] = {9216, 2304, 576, 144};
    const size_t vbase[4] = {VB0, VB1, VB2, VB3};

#pragma unroll
    for (int lv = 0; lv < 4; ++lv) {
        const int W = dims[lv];
        const float fx = sRef[lq][lv * 2]     * (float)W - 0.5f;
        const float fy = sRef[lq][lv * 2 + 1] * (float)W - 0.5f;
        const unsigned short* vb =
            vals + vbase[lv] + (size_t)n * hwsz[lv] * 256 + h * 32 + lg * 8;
#pragma unroll
        for (int p = 0; p < 4; ++p) {
            const float2 xy = *(const float2*)&sOff[lq][((lv * 4 + p) * 8 + h) * 2];
            const float x = fx + xy.x;
            const float y = fy + xy.y;
            const float x0f = floorf(x), y0f = floorf(y);
            const float wx = x - x0f, wy = y - y0f;
            const int x0 = (int)x0f, y0 = (int)y0f;
            const float aw = e[lv * 4 + p] * inv;
            const float vx0 = ((unsigned)x0       < (unsigned)W) ? 1.f - wx : 0.f;
            const float vx1 = ((unsigned)(x0 + 1) < (unsigned)W) ? wx       : 0.f;
            const float vy0 = ((unsigned)y0       < (unsigned)W) ? 1.f - wy : 0.f;
            const float vy1 = ((unsigned)(y0 + 1) < (unsigned)W) ? wy       : 0.f;
            const int cx0 = min(max(x0, 0), W - 1);
            const int cx1 = min(max(x0 + 1, 0), W - 1);
            const int cy0 = min(max(y0, 0), W - 1) * W;
            const int cy1 = min(max(y0 + 1, 0), W - 1) * W;
            acc8(vb + (size_t)(cy0 + cx0) * 256, aw * vy0 * vx0, acc);
            acc8(vb + (size_t)(cy0 + cx1) * 256, aw * vy0 * vx1, acc);
            acc8(vb + (size_t)(cy1 + cx0) * 256, aw * vy1 * vx0, acc);
            acc8(vb + (size_t)(cy1 + cx1) * 256, aw * vy1 * vx1, acc);
        }
    }
    uint4 o;
    o.x = (unsigned)f2bf(acc[0]) | ((unsigned)f2bf(acc[1]) << 16);
    o.y = (unsigned)f2bf(acc[2]) | ((unsigned)f2bf(acc[3]) << 16);
    o.z = (unsigned)f2bf(acc[4]) | ((unsigned)f2bf(acc[5]) << 16);
    o.w = (unsigned)f2bf(acc[6]) | ((unsigned)f2bf(acc[7]) << 16);
    *(uint4*)&msout[(size_t)b * 256 + h * 32 + lg * 8] = o;
}

// ---------------------------------------------------------------------------
// LN (unchanged)
// ---------------------------------------------------------------------------
__global__ __launch_bounds__(256) void ln_kernel(
    const float* __restrict__ a, const float* __restrict__ b,
    const float* __restrict__ g, const float* __restrict__ be,
    float* __restrict__ out32, unsigned short* __restrict__ out16)
{
    const int t = threadIdx.x, w = t >> 6, l = t & 63;
    const int row = blockIdx.x * 4 + w;
    const size_t base = (size_t)row * 256 + l * 4;
    const float4 av = *(const float4*)&a[base];
    const float4 bv = *(const float4*)&b[base];
    const float x0 = av.x + bv.x, x1 = av.y + bv.y, x2 = av.z + bv.z, x3 = av.w + bv.w;
    float s  = x0 + x1 + x2 + x3;
    float s2 = x0 * x0 + x1 * x1 + x2 * x2 + x3 * x3;
#pragma unroll
    for (int o = 32; o; o >>= 1) { s += __shfl_xor(s, o); s2 += __shfl_xor(s2, o); }
    const float mean = s * (1.f / 256.f);
    const float rstd = rsqrtf(s2 * (1.f / 256.f) - mean * mean + 1e-5f);
    const float4 gv = *(const float4*)&g[l * 4];
    const float4 ev = *(const float4*)&be[l * 4];
    const float y0 = (x0 - mean) * rstd * gv.x + ev.x;
    const float y1 = (x1 - mean) * rstd * gv.y + ev.y;
    const float y2 = (x2 - mean) * rstd * gv.z + ev.z;
    const float y3 = (x3 - mean) * rstd * gv.w + ev.w;
    float4 o4; o4.x = y0; o4.y = y1; o4.z = y2; o4.w = y3;
    *(float4*)&out32[base] = o4;
    if (out16) {
        ushort4 o;
        o.x = f2bf(y0); o.y = f2bf(y1); o.z = f2bf(y2); o.w = f2bf(y3);
        *(ushort4*)&out16[base] = o;
    }
}

// ---------------------------------------------------------------------------
extern "C" void kernel_launch(void* const* d_in, const int* in_sizes, int n_in,
                              void* d_out, int out_size, void* d_ws, size_t ws_size,
                              hipStream_t stream)
{
    const float* tgt   = (const float*)d_in[0];
    const float* ref   = (const float*)d_in[1];
    const float* src0  = (const float*)d_in[2];
    const float* src1  = (const float*)d_in[3];
    const float* src2  = (const float*)d_in[4];
    const float* src3  = (const float*)d_in[5];
    const float* Wv0   = (const float*)d_in[6];
    const float* bv0   = (const float*)d_in[7];
    const float* Wv1   = (const float*)d_in[8];
    const float* bv1   = (const float*)d_in[9];
    const float* Woff  = (const float*)d_in[10];
    const float* boff  = (const float*)d_in[11];
    const float* Wattn = (const float*)d_in[12];
    const float* battn = (const float*)d_in[13];
    const float* Wout  = (const float*)d_in[14];
    const float* bout  = (const float*)d_in[15];
    const float* g1    = (const float*)d_in[16];
    const float* be1   = (const float*)d_in[17];
    const float* W1    = (const float*)d_in[18];
    const float* b1    = (const float*)d_in[19];
    const float* W2    = (const float*)d_in[20];
    const float* b2    = (const float*)d_in[21];
    const float* g3    = (const float*)d_in[22];
    const float* be3   = (const float*)d_in[23];

    char* w8 = (char*)d_ws;
    unsigned short* vals_bf  = (unsigned short*)(w8 + 0);
    unsigned short* tgt_bf   = (unsigned short*)(w8 + 50135040);
    unsigned short* Btoa     = (unsigned short*)(w8 + 54329344);
    unsigned short* WoT      = (unsigned short*)(w8 + 54525952);
    unsigned short* W1T      = (unsigned short*)(w8 + 54657024);
    unsigned short* W2T      = (unsigned short*)(w8 + 55181312);
    unsigned short* ffn1_bf  = (unsigned short*)(w8 + 55705600);
    unsigned short* msout_bf = (unsigned short*)(w8 + 72482816);
    unsigned short* tbuf16   = (unsigned short*)(w8 + 76677120);
    float* boa    = (float*)(w8 + 80871424);
    float* offlog = (float*)(w8 + 80872960);
    float* ms2    = (float*)(w8 + 93455872);
    float* tbuf32 = (float*)(w8 + 101844480);
    float* ffn2   = (float*)(w8 + 110233088);
    // src staging lives inside the ms2 region (written only later by Wout-GEMM)
    unsigned short* src0p = (unsigned short*)(w8 + 93455872);            // 4,718,592 B
    unsigned short* src1b = (unsigned short*)(w8 + 93455872 + 4718592);  // 1,179,648 B
    unsigned short* src2p = (unsigned short*)(w8 + 93455872 + 5898240);  //   294,912 B
    unsigned short* src3b = (unsigned short*)(w8 + 93455872 + 6193152);  //    73,728 B
    unsigned short* WvT0  = (unsigned short*)(w8 + 93455872 + 6266880);  //    16,384 B
    unsigned short* WvT1  = (unsigned short*)(w8 + 93455872 + 6283264);  //    16,384 B

    const dim3 blk(256);

    prep_kernel<<<4053, blk, 0, stream>>>(tgt, Woff, Wattn, Wout, W1, W2, boff, battn,
                                          src0, src1, src2, src3, Wv0, Wv1,
                                          tgt_bf, Btoa, WoT, W1T, W2T, boa,
                                          src0p, src1b, src2p, src3b, WvT0, WvT1);

    // value projection: single dispatch, all levels (K=32, zero-padded)
    vproj_gemm<<<dim3(2, 765), blk, 0, stream>>>(src0p, src1b, src2p, src3b,
                                                 WvT0, WvT1, bv0, bv1, vals_bf);

    // offlog = tgt @ [Woff|Wattn] + [boff|battn]   (8192 x 384, K=256)
    gemm_bf16<64, 128, 0, 0><<<dim3(3, 128), blk, 0, stream>>>(
        tgt_bf, Btoa, boa, offlog, (unsigned short*)nullptr, 8192, 384, 256);
    sampler_kernel<<<1024, blk, 0, stream>>>(vals_bf, offlog, ref, msout_bf);

    // ms2 = msout @ Wout + bout   (256 blocks)
    gemm_bf16<64, 128, 0, 0><<<dim3(2, 128), blk, 0, stream>>>(
        msout_bf, WoT, bout, ms2, (unsigned short*)nullptr, 8192, 256, 256);
    // t = LN(tgt + ms2) -> fp32 + bf16
    ln_kernel<<<2048, blk, 0, stream>>>(tgt, ms2, g1, be1, tbuf32, tbuf16);

    // ffn1 = relu(t @ W1 + b1) -> bf16  (512 blocks)
    gemm_bf16<128, 128, 1, 1><<<dim3(8, 64), blk, 0, stream>>>(
        tbuf16, W1T, b1, (float*)nullptr, ffn1_bf, 8192, 1024, 256);
    // ffn2 = ffn1 @ W2 + b2 -> fp32  (256 blocks)
    gemm_bf16<64, 128, 0, 0><<<dim3(2, 128), blk, 0, stream>>>(
        ffn1_bf, W2T, b2, ffn2, (unsigned short*)nullptr, 8192, 256, 1024);
    // out = LN(t + ffn2)
    ln_kernel<<<2048, blk, 0, stream>>>(tbuf32, ffn2, g3, be3, (float*)d_out,
                                        (unsigned short*)nullptr);
}

// Round 11
// 207.931 us; speedup vs baseline: 2.0744x; 1.0020x over previous
//
#include <hip/hip_runtime.h>
#include <math.h>

// ---------------------------------------------------------------------------
// Deformable-attention decoder layer. bf16 MFMA GEMMs (templated tiles,
// swizzled LDS, 2-phase prefetch); value projection reads fp32 srcs directly
// (reg-stage + cvt + swizzled ds_write); branchless 2-query/wave sampler.
// N=8, Lq=1024, D=256, NH=8, NL=4, NP=4, DH=32, DFFN=1024
// ---------------------------------------------------------------------------

typedef __bf16 bf16x8 __attribute__((ext_vector_type(8)));
typedef float  f32x4  __attribute__((ext_vector_type(4)));
typedef unsigned short ushort8 __attribute__((ext_vector_type(8)));

#define VB0 0
#define VB1 18874368   // 8*9216*256
#define VB2 23592960   // +8*2304*256
#define VB3 24772608   // +8*576*256
#define VTOT 25067520

__device__ __forceinline__ unsigned short f2bf(float f) {
    unsigned u = __float_as_uint(f);
    u += 0x7FFF + ((u >> 16) & 1);           // RNE
    return (unsigned short)(u >> 16);
}

__device__ __forceinline__ void gload16(const void* g, void* l) {
    __builtin_amdgcn_global_load_lds(
        (const __attribute__((address_space(1))) unsigned int*)g,
        (__attribute__((address_space(3))) unsigned int*)l, 16, 0, 0);
}

// ---------------------------------------------------------------------------
// prep:
//   blocks 0..2047    : tgt -> bf16
//   block  2048       : bias concat + WvT0/WvT1 (256x32 bf16, K-padded)
//   blocks 2049..2216 : coalesced 64x64 tile transposes of Woff/Wattn/Wout/W1/W2
// ---------------------------------------------------------------------------
__global__ __launch_bounds__(256) void prep_kernel(
    const float* __restrict__ tgt, const float* __restrict__ Woff,
    const float* __restrict__ Wattn, const float* __restrict__ Wout,
    const float* __restrict__ W1, const float* __restrict__ W2,
    const float* __restrict__ boff, const float* __restrict__ battn,
    const float* __restrict__ Wv0, const float* __restrict__ Wv1,
    unsigned short* __restrict__ tgt_bf, unsigned short* __restrict__ Btoa,
    unsigned short* __restrict__ WoT, unsigned short* __restrict__ W1T,
    unsigned short* __restrict__ W2T, float* __restrict__ boa,
    unsigned short* __restrict__ WvT0, unsigned short* __restrict__ WvT1)
{
    __shared__ float sT[64][65];
    const int b = blockIdx.x, t = threadIdx.x;
    if (b < 2048) {
        const int i = (b * 256 + t) * 4;
        const float4 v = *(const float4*)&tgt[i];
        ushort4 o;
        o.x = f2bf(v.x); o.y = f2bf(v.y); o.z = f2bf(v.z); o.w = f2bf(v.w);
        *(ushort4*)&tgt_bf[i] = o;
        return;
    }
    if (b == 2048) {
        if (t < 384) boa[t] = (t < 256) ? boff[t] : battn[t - 256];
#pragma unroll
        for (int k = 0; k < 16; ++k) {
            WvT0[t * 32 + k]      = f2bf(Wv0[k * 256 + t]);
            WvT0[t * 32 + 16 + k] = 0;
        }
#pragma unroll
        for (int k = 0; k < 32; ++k)
            WvT1[t * 32 + k] = f2bf(Wv1[k * 256 + t]);
        return;
    }
    int tb = b - 2049;
    const float* src; unsigned short* dst; int srcN, dstK, tn, tk;
    if (tb < 16)       { src = Woff;  dst = Btoa;          srcN = 256;  dstK = 256;  tn = tb >> 2; tk = tb & 3; }
    else if (tb < 24)  { tb -= 16; src = Wattn; dst = Btoa + 65536; srcN = 128; dstK = 256; tn = tb >> 2; tk = tb & 3; }
    else if (tb < 40)  { tb -= 24; src = Wout;  dst = WoT; srcN = 256;  dstK = 256;  tn = tb >> 2; tk = tb & 3; }
    else if (tb < 104) { tb -= 40; src = W1;    dst = W1T; srcN = 1024; dstK = 256;  tn = tb >> 2; tk = tb & 3; }
    else               { tb -= 104; src = W2;   dst = W2T; srcN = 256;  dstK = 1024; tn = tb >> 4; tk = tb & 15; }
    const int n0 = tn * 64, k0 = tk * 64;
    const int j = t & 63, i0 = t >> 6;
#pragma unroll
    for (int s = 0; s < 16; ++s) {
        const int i = i0 + s * 4;
        sT[i][j] = src[(size_t)(k0 + i) * srcN + n0 + j];
    }
    __syncthreads();
#pragma unroll
    for (int s = 0; s < 16; ++s) {
        const int nr = i0 + s * 4;
        dst[(size_t)(n0 + nr) * dstK + k0 + j] = f2bf(sT[j][nr]);
    }
}

// ---------------------------------------------------------------------------
// bf16 MFMA GEMM, templated tile: C(MxN) = A(MxK) @ Bt(NxK)^T + bias.
// BK=32, 4 waves (2x2); wave covers (BM/2)x(BN/2); frags (BM/32)x(BN/32).
// XOR-swizzled LDS, double-buffered, 2-phase prefetch.
// ---------------------------------------------------------------------------
template <int BM, int BN, int RELU, int OUTBF16>
__global__ __launch_bounds__(256) void gemm_bf16(
    const unsigned short* __restrict__ A, const unsigned short* __restrict__ Bt,
    const float* __restrict__ bias, float* __restrict__ C32,
    unsigned short* __restrict__ C16, int M, int N, int K)
{
    constexpr int MF = BM / 32, NF = BN / 32;      // frags per wave
    constexpr int CA = BM / 16, CB = BN / 16;      // 16-row staging chunks
    constexpr int CPW = (CA + CB) / 4;             // chunks per wave

    __shared__ unsigned short As[2][BM * 32];
    __shared__ unsigned short Bs[2][BN * 32];

    const int t = threadIdx.x, wv = t >> 6, l = t & 63;
    const int m0 = blockIdx.y * BM, n0 = blockIdx.x * BN;
    const int wm = wv >> 1, wn = wv & 1;
    const int lr = l >> 2, sl = l & 3;
    const int swsl = sl ^ ((lr >> 1) & 3);     // pre-swizzled source slot
    const int fr = l & 15, kg = l >> 4;
    const int rsw = (fr >> 1) & 3;             // read-side swizzle

    f32x4 acc[MF][NF];
#pragma unroll
    for (int i = 0; i < MF; ++i)
#pragma unroll
        for (int j = 0; j < NF; ++j) acc[i][j] = (f32x4){0.f, 0.f, 0.f, 0.f};

#define STAGE(bufi, k0)                                                        \
    do {                                                                       \
        _Pragma("unroll")                                                      \
        for (int cc = 0; cc < CPW; ++cc) {                                     \
            const int ch = wv * CPW + cc;                                      \
            if (ch < CA) {                                                     \
                gload16(A + (size_t)(m0 + ch * 16 + lr) * K + (k0) + swsl * 8, \
                        &As[bufi][ch * 512]);                                  \
            } else {                                                           \
                const int cb2 = ch - CA;                                       \
                gload16(Bt + (size_t)(n0 + cb2 * 16 + lr) * K + (k0) + swsl * 8,\
                        &Bs[bufi][cb2 * 512]);                                 \
            }                                                                  \
        }                                                                      \
    } while (0)

    const int NT = K >> 5;
    STAGE(0, 0);
    asm volatile("s_waitcnt vmcnt(0)" ::: "memory");
    __syncthreads();

    for (int tt = 0; tt < NT; ++tt) {
        const int cur = tt & 1;
        if (tt + 1 < NT) STAGE(cur ^ 1, (tt + 1) * 32);

        bf16x8 af[MF], bfr[NF];
#pragma unroll
        for (int i = 0; i < MF; ++i)
            af[i] = *(const bf16x8*)&As[cur][(wm * (MF * 16) + i * 16 + fr) * 32 + (kg ^ rsw) * 8];
#pragma unroll
        for (int j = 0; j < NF; ++j)
            bfr[j] = *(const bf16x8*)&Bs[cur][(wn * (NF * 16) + j * 16 + fr) * 32 + (kg ^ rsw) * 8];
#pragma unroll
        for (int i = 0; i < MF; ++i)
#pragma unroll
            for (int j = 0; j < NF; ++j)
                acc[i][j] = __builtin_amdgcn_mfma_f32_16x16x32_bf16(af[i], bfr[j], acc[i][j], 0, 0, 0);

        asm volatile("s_waitcnt vmcnt(0)" ::: "memory");
        __syncthreads();
    }
#undef STAGE

    const int q4 = (l >> 4) * 4;
#pragma unroll
    for (int j = 0; j < NF; ++j) {
        const int col = n0 + wn * (NF * 16) + j * 16 + fr;
        const float bj = bias[col];
#pragma unroll
        for (int i = 0; i < MF; ++i) {
#pragma unroll
            for (int r = 0; r < 4; ++r) {
                const int row = m0 + wm * (MF * 16) + i * 16 + q4 + r;
                float v = acc[i][j][r] + bj;
                if (RELU) v = fmaxf(v, 0.f);
                if (OUTBF16) C16[(size_t)row * N + col] = f2bf(v);
                else         C32[(size_t)row * N + col] = v;
            }
        }
    }
}

// ---------------------------------------------------------------------------
// value projection: single dispatch, all 4 levels, A read DIRECTLY from fp32
// (reg-stage + cvt + swizzled ds_write; K=16 levels zero-padded to 32).
// LDS layout identical to gemm_bf16: LDS[row][slot] = A[row][slot^((row>>1)&3)].
// blockIdx.y: [0,576) L0 | [576,720) L1 | [720,756) L2 | [756,765) L3.
// ---------------------------------------------------------------------------
__global__ __launch_bounds__(256) void vproj_gemm(
    const float* __restrict__ src0, const float* __restrict__ src1,
    const float* __restrict__ src2, const float* __restrict__ src3,
    const unsigned short* __restrict__ WvT0, const unsigned short* __restrict__ WvT1,
    const float* __restrict__ bv0, const float* __restrict__ bv1,
    unsigned short* __restrict__ vals)
{
    __shared__ unsigned short As[128 * 32];
    __shared__ unsigned short Bs[128 * 32];

    const int ly = blockIdx.y;
    const float* A32; const unsigned short* Bt; const float* bias;
    size_t ob; int lm, Kr;
    if (ly < 576)      { A32 = src0; Bt = WvT0; bias = bv0; ob = VB0; lm = ly;       Kr = 16; }
    else if (ly < 720) { A32 = src1; Bt = WvT1; bias = bv1; ob = VB1; lm = ly - 576; Kr = 32; }
    else if (ly < 756) { A32 = src2; Bt = WvT0; bias = bv0; ob = VB2; lm = ly - 720; Kr = 16; }
    else               { A32 = src3; Bt = WvT1; bias = bv1; ob = VB3; lm = ly - 756; Kr = 32; }

    const int t = threadIdx.x, wv = t >> 6, l = t & 63;
    const int m0 = lm * 128, n0 = blockIdx.x * 128;
    const int wm = wv >> 1, wn = wv & 1;
    const int lr = l >> 2, sl = l & 3;
    const int swsl = sl ^ ((lr >> 1) & 3);
    const int fr = l & 15, kg = l >> 4;
    const int rsw = (fr >> 1) & 3;

    // ---- stage B via global_load_lds: 8 chunks, wave stages 2 ----
#pragma unroll
    for (int cc = 0; cc < 2; ++cc) {
        const int ch = wv * 2 + cc;
        gload16(Bt + (size_t)(n0 + ch * 16 + lr) * 32 + swsl * 8, &Bs[ch * 512]);
    }

    // ---- stage A from fp32: thread t covers row r, half hh (16 cols) ----
    {
        const int r = t >> 1, hh = t & 1;
        const int rs = (r >> 1) & 3;
        if (Kr == 32) {
            const float4* sp = (const float4*)(A32 + (size_t)(m0 + r) * 32 + hh * 16);
            const float4 a0 = sp[0], a1 = sp[1], a2 = sp[2], a3 = sp[3];
            ushort8 w0, w1;
            w0[0] = f2bf(a0.x); w0[1] = f2bf(a0.y); w0[2] = f2bf(a0.z); w0[3] = f2bf(a0.w);
            w0[4] = f2bf(a1.x); w0[5] = f2bf(a1.y); w0[6] = f2bf(a1.z); w0[7] = f2bf(a1.w);
            w1[0] = f2bf(a2.x); w1[1] = f2bf(a2.y); w1[2] = f2bf(a2.z); w1[3] = f2bf(a2.w);
            w1[4] = f2bf(a3.x); w1[5] = f2bf(a3.y); w1[6] = f2bf(a3.z); w1[7] = f2bf(a3.w);
            *(ushort8*)&As[r * 32 + ((hh * 2 + 0) ^ rs) * 8] = w0;
            *(ushort8*)&As[r * 32 + ((hh * 2 + 1) ^ rs) * 8] = w1;
        } else {
            if (hh == 0) {
                const float4* sp = (const float4*)(A32 + (size_t)(m0 + r) * 16);
                const float4 a0 = sp[0], a1 = sp[1], a2 = sp[2], a3 = sp[3];
                ushort8 w0, w1;
                w0[0] = f2bf(a0.x); w0[1] = f2bf(a0.y); w0[2] = f2bf(a0.z); w0[3] = f2bf(a0.w);
                w0[4] = f2bf(a1.x); w0[5] = f2bf(a1.y); w0[6] = f2bf(a1.z); w0[7] = f2bf(a1.w);
                w1[0] = f2bf(a2.x); w1[1] = f2bf(a2.y); w1[2] = f2bf(a2.z); w1[3] = f2bf(a2.w);
                w1[4] = f2bf(a3.x); w1[5] = f2bf(a3.y); w1[6] = f2bf(a3.z); w1[7] = f2bf(a3.w);
                *(ushort8*)&As[r * 32 + ((0) ^ rs) * 8] = w0;
                *(ushort8*)&As[r * 32 + ((1) ^ rs) * 8] = w1;
            } else {
                const ushort8 z = {0, 0, 0, 0, 0, 0, 0, 0};
                *(ushort8*)&As[r * 32 + ((2) ^ rs) * 8] = z;
                *(ushort8*)&As[r * 32 + ((3) ^ rs) * 8] = z;
            }
        }
    }
    asm volatile("s_waitcnt vmcnt(0)" ::: "memory");
    __syncthreads();

    f32x4 acc[4][4];
#pragma unroll
    for (int i = 0; i < 4; ++i)
#pragma unroll
        for (int j = 0; j < 4; ++j) acc[i][j] = (f32x4){0.f, 0.f, 0.f, 0.f};

    bf16x8 af[4], bfr[4];
#pragma unroll
    for (int i = 0; i < 4; ++i)
        af[i] = *(const bf16x8*)&As[(wm * 64 + i * 16 + fr) * 32 + (kg ^ rsw) * 8];
#pragma unroll
    for (int j = 0; j < 4; ++j)
        bfr[j] = *(const bf16x8*)&Bs[(wn * 64 + j * 16 + fr) * 32 + (kg ^ rsw) * 8];
#pragma unroll
    for (int i = 0; i < 4; ++i)
#pragma unroll
        for (int j = 0; j < 4; ++j)
            acc[i][j] = __builtin_amdgcn_mfma_f32_16x16x32_bf16(af[i], bfr[j], acc[i][j], 0, 0, 0);

    const int q4 = (l >> 4) * 4;
#pragma unroll
    for (int j = 0; j < 4; ++j) {
        const int col = n0 + wn * 64 + j * 16 + fr;
        const float bj = bias[col];
#pragma unroll
        for (int i = 0; i < 4; ++i) {
#pragma unroll
            for (int r = 0; r < 4; ++r) {
                const int row = m0 + wm * 64 + i * 16 + q4 + r;
                vals[ob + (size_t)row * 256 + col] = f2bf(acc[i][j][r] + bj);
            }
        }
    }
}

// ---------------------------------------------------------------------------
// sampler (unchanged)
// ---------------------------------------------------------------------------
__device__ __forceinline__ void acc8(const unsigned short* p, float w, float* a)
{
    const uint4 u = *(const uint4*)p;
    a[0] = fmaf(w, __uint_as_float(u.x << 16), a[0]);
    a[1] = fmaf(w, __uint_as_float(u.x & 0xffff0000u), a[1]);
    a[2] = fmaf(w, __uint_as_float(u.y << 16), a[2]);
    a[3] = fmaf(w, __uint_as_float(u.y & 0xffff0000u), a[3]);
    a[4] = fmaf(w, __uint_as_float(u.z << 16), a[4]);
    a[5] = fmaf(w, __uint_as_float(u.z & 0xffff0000u), a[5]);
    a[6] = fmaf(w, __uint_as_float(u.w << 16), a[6]);
    a[7] = fmaf(w, __uint_as_float(u.w & 0xffff0000u), a[7]);
}

__global__ __launch_bounds__(256) void sampler_kernel(
    const unsigned short* __restrict__ vals, const float* __restrict__ offlog,
    const float* __restrict__ ref, unsigned short* __restrict__ msout)
{
    __shared__ float sOff[8][256];
    __shared__ float sLog[8][128];
    __shared__ float sRef[8][8];

    const int t = threadIdx.x, w = t >> 6, l = t & 63;
    const int qbase = blockIdx.x * 8;

    for (int j = l; j < 768; j += 64) {
        const int second = (j >= 384);
        const int lq = w * 2 + second;
        const int jj = second ? j - 384 : j;      // 384 is not pow2: no masking
        const float v = offlog[(size_t)(qbase + lq) * 384 + jj];
        if (jj < 256) {
            const int h = jj >> 5, r = jj & 31;
            sOff[lq][(r >> 1) * 16 + h * 2 + (r & 1)] = v;
        } else {
            const int j2 = jj - 256;
            sLog[lq][(j2 & 15) * 8 + (j2 >> 4)] = v;
        }
    }
    if (l < 16)
        sRef[w * 2 + (l >> 3)][l & 7] = ref[(size_t)(qbase + w * 2 + (l >> 3)) * 8 + (l & 7)];
    __syncthreads();

    const int lq = w * 2 + (l >> 5);
    const int b  = qbase + lq;
    const int n  = b >> 10;
    const int h  = (l >> 2) & 7;
    const int lg = l & 3;

    float mx = -1e30f;
#pragma unroll
    for (int i = 0; i < 16; ++i) mx = fmaxf(mx, sLog[lq][i * 8 + h]);
    float e[16], s = 0.f;
#pragma unroll
    for (int i = 0; i < 16; ++i) { e[i] = __expf(sLog[lq][i * 8 + h] - mx); s += e[i]; }
    const float inv = 1.f / s;

    float acc[8] = {0.f, 0.f, 0.f, 0.f, 0.f, 0.f, 0.f, 0.f};
    const int dims[4] = {96, 48, 24, 12};
    const int hwsz[4] = {9216, 2304, 576, 144};
    const size_t vbase[4] = {VB0, VB1, VB2, VB3};

#pragma unroll
    for (int lv = 0; lv < 4; ++lv) {
        const int W = dims[lv];
        const float fx = sRef[lq][lv * 2]     * (float)W - 0.5f;
        const float fy = sRef[lq][lv * 2 + 1] * (float)W - 0.5f;
        const unsigned short* vb =
            vals + vbase[lv] + (size_t)n * hwsz[lv] * 256 + h * 32 + lg * 8;
#pragma unroll
        for (int p = 0; p < 4; ++p) {
            const float2 xy = *(const float2*)&sOff[lq][((lv * 4 + p) * 8 + h) * 2];
            const float x = fx + xy.x;
            const float y = fy + xy.y;
            const float x0f = floorf(x), y0f = floorf(y);
            const float wx = x - x0f, wy = y - y0f;
            const int x0 = (int)x0f, y0 = (int)y0f;
            const float aw = e[lv * 4 + p] * inv;
            const float vx0 = ((unsigned)x0       < (unsigned)W) ? 1.f - wx : 0.f;
            const float vx1 = ((unsigned)(x0 + 1) < (unsigned)W) ? wx       : 0.f;
            const float vy0 = ((unsigned)y0       < (unsigned)W) ? 1.f - wy : 0.f;
            const float vy1 = ((unsigned)(y0 + 1) < (unsigned)W) ? wy       : 0.f;
            const int cx0 = min(max(x0, 0), W - 1);
            const int cx1 = min(max(x0 + 1, 0), W - 1);
            const int cy0 = min(max(y0, 0), W - 1) * W;
            const int cy1 = min(max(y0 + 1, 0), W - 1) * W;
            acc8(vb + (size_t)(cy0 + cx0) * 256, aw * vy0 * vx0, acc);
            acc8(vb + (size_t)(cy0 + cx1) * 256, aw * vy0 * vx1, acc);
            acc8(vb + (size_t)(cy1 + cx0) * 256, aw * vy1 * vx0, acc);
            acc8(vb + (size_t)(cy1 + cx1) * 256, aw * vy1 * vx1, acc);
        }
    }
    uint4 o;
    o.x = (unsigned)f2bf(acc[0]) | ((unsigned)f2bf(acc[1]) << 16);
    o.y = (unsigned)f2bf(acc[2]) | ((unsigned)f2bf(acc[3]) << 16);
    o.z = (unsigned)f2bf(acc[4]) | ((unsigned)f2bf(acc[5]) << 16);
    o.w = (unsigned)f2bf(acc[6]) | ((unsigned)f2bf(acc[7]) << 16);
    *(uint4*)&msout[(size_t)b * 256 + h * 32 + lg * 8] = o;
}

// ---------------------------------------------------------------------------
// LN (unchanged)
// ---------------------------------------------------------------------------
__global__ __launch_bounds__(256) void ln_kernel(
    const float* __restrict__ a, const float* __restrict__ b,
    const float* __restrict__ g, const float* __restrict__ be,
    float* __restrict__ out32, unsigned short* __restrict__ out16)
{
    const int t = threadIdx.x, w = t >> 6, l = t & 63;
    const int row = blockIdx.x * 4 + w;
    const size_t base = (size_t)row * 256 + l * 4;
    const float4 av = *(const float4*)&a[base];
    const float4 bv = *(const float4*)&b[base];
    const float x0 = av.x + bv.x, x1 = av.y + bv.y, x2 = av.z + bv.z, x3 = av.w + bv.w;
    float s  = x0 + x1 + x2 + x3;
    float s2 = x0 * x0 + x1 * x1 + x2 * x2 + x3 * x3;
#pragma unroll
    for (int o = 32; o; o >>= 1) { s += __shfl_xor(s, o); s2 += __shfl_xor(s2, o); }
    const float mean = s * (1.f / 256.f);
    const float rstd = rsqrtf(s2 * (1.f / 256.f) - mean * mean + 1e-5f);
    const float4 gv = *(const float4*)&g[l * 4];
    const float4 ev = *(const float4*)&be[l * 4];
    const float y0 = (x0 - mean) * rstd * gv.x + ev.x;
    const float y1 = (x1 - mean) * rstd * gv.y + ev.y;
    const float y2 = (x2 - mean) * rstd * gv.z + ev.z;
    const float y3 = (x3 - mean) * rstd * gv.w + ev.w;
    float4 o4; o4.x = y0; o4.y = y1; o4.z = y2; o4.w = y3;
    *(float4*)&out32[base] = o4;
    if (out16) {
        ushort4 o;
        o.x = f2bf(y0); o.y = f2bf(y1); o.z = f2bf(y2); o.w = f2bf(y3);
        *(ushort4*)&out16[base] = o;
    }
}

// ---------------------------------------------------------------------------
extern "C" void kernel_launch(void* const* d_in, const int* in_sizes, int n_in,
                              void* d_out, int out_size, void* d_ws, size_t ws_size,
                              hipStream_t stream)
{
    const float* tgt   = (const float*)d_in[0];
    const float* ref   = (const float*)d_in[1];
    const float* src0  = (const float*)d_in[2];
    const float* src1  = (const float*)d_in[3];
    const float* src2  = (const float*)d_in[4];
    const float* src3  = (const float*)d_in[5];
    const float* Wv0   = (const float*)d_in[6];
    const float* bv0   = (const float*)d_in[7];
    const float* Wv1   = (const float*)d_in[8];
    const float* bv1   = (const float*)d_in[9];
    const float* Woff  = (const float*)d_in[10];
    const float* boff  = (const float*)d_in[11];
    const float* Wattn = (const float*)d_in[12];
    const float* battn = (const float*)d_in[13];
    const float* Wout  = (const float*)d_in[14];
    const float* bout  = (const float*)d_in[15];
    const float* g1    = (const float*)d_in[16];
    const float* be1   = (const float*)d_in[17];
    const float* W1    = (const float*)d_in[18];
    const float* b1    = (const float*)d_in[19];
    const float* W2    = (const float*)d_in[20];
    const float* b2    = (const float*)d_in[21];
    const float* g3    = (const float*)d_in[22];
    const float* be3   = (const float*)d_in[23];

    char* w8 = (char*)d_ws;
    unsigned short* vals_bf  = (unsigned short*)(w8 + 0);
    unsigned short* tgt_bf   = (unsigned short*)(w8 + 50135040);
    unsigned short* Btoa     = (unsigned short*)(w8 + 54329344);
    unsigned short* WoT      = (unsigned short*)(w8 + 54525952);
    unsigned short* W1T      = (unsigned short*)(w8 + 54657024);
    unsigned short* W2T      = (unsigned short*)(w8 + 55181312);
    unsigned short* ffn1_bf  = (unsigned short*)(w8 + 55705600);
    unsigned short* msout_bf = (unsigned short*)(w8 + 72482816);
    unsigned short* tbuf16   = (unsigned short*)(w8 + 76677120);
    float* boa    = (float*)(w8 + 80871424);
    float* offlog = (float*)(w8 + 80872960);
    float* ms2    = (float*)(w8 + 93455872);
    float* tbuf32 = (float*)(w8 + 101844480);
    float* ffn2   = (float*)(w8 + 110233088);
    // WvT staging lives inside the ms2 region (ms2 is written only later, by
    // the Wout-GEMM, after vproj has consumed WvT; prep rewrites each launch)
    unsigned short* WvT0  = (unsigned short*)(w8 + 93455872 + 6266880);  // 16,384 B
    unsigned short* WvT1  = (unsigned short*)(w8 + 93455872 + 6283264);  // 16,384 B

    const dim3 blk(256);

    prep_kernel<<<2217, blk, 0, stream>>>(tgt, Woff, Wattn, Wout, W1, W2, boff, battn,
                                          Wv0, Wv1,
                                          tgt_bf, Btoa, WoT, W1T, W2T, boa, WvT0, WvT1);

    // value projection: single dispatch, all levels, direct fp32 A-staging
    vproj_gemm<<<dim3(2, 765), blk, 0, stream>>>(src0, src1, src2, src3,
                                                 WvT0, WvT1, bv0, bv1, vals_bf);

    // offlog = tgt @ [Woff|Wattn] + [boff|battn]   (8192 x 384, K=256)
    gemm_bf16<64, 128, 0, 0><<<dim3(3, 128), blk, 0, stream>>>(
        tgt_bf, Btoa, boa, offlog, (unsigned short*)nullptr, 8192, 384, 256);
    sampler_kernel<<<1024, blk, 0, stream>>>(vals_bf, offlog, ref, msout_bf);

    // ms2 = msout @ Wout + bout   (256 blocks)
    gemm_bf16<64, 128, 0, 0><<<dim3(2, 128), blk, 0, stream>>>(
        msout_bf, WoT, bout, ms2, (unsigned short*)nullptr, 8192, 256, 256);
    // t = LN(tgt + ms2) -> fp32 + bf16
    ln_kernel<<<2048, blk, 0, stream>>>(tgt, ms2, g1, be1, tbuf32, tbuf16);

    // ffn1 = relu(t @ W1 + b1) -> bf16  (512 blocks)
    gemm_bf16<128, 128, 1, 1><<<dim3(8, 64), blk, 0, stream>>>(
        tbuf16, W1T, b1, (float*)nullptr, ffn1_bf, 8192, 1024, 256);
    // ffn2 = ffn1 @ W2 + b2 -> fp32  (256 blocks)
    gemm_bf16<64, 128, 0, 0><<<dim3(2, 128), blk, 0, stream>>>(
        ffn1_bf, W2T, b2, ffn2, (unsigned short*)nullptr, 8192, 256, 1024);
    // out = LN(t + ffn2)
    ln_kernel<<<2048, blk, 0, stream>>>(tbuf32, ffn2, g3, be3, (float*)d_out,
                                        (unsigned short*)nullptr);
}